// Round 1
// baseline (565.945 us; speedup 1.0000x reference)
//
#include <hip/hip_runtime.h>
#include <hip/hip_bf16.h>

// Dims fixed by the problem
#define DIN 128
#define DHID 128
#define DOUT 64

static inline size_t al256(size_t x) { return (x + 255) & ~(size_t)255; }

// ---------------- mask encoding auto-detect ----------------
// train_mask is bool in the reference; harness may pass it as raw u8,
// int32, or float32. Detect from bit patterns: flag 0=u8, 1=int32, 2=f32.
__global__ void detect_mask_kernel(const int* __restrict__ tm, int n_int, int* __restrict__ flag) {
    __shared__ int has_float, has_other;
    if (threadIdx.x == 0) { has_float = 0; has_other = 0; }
    __syncthreads();
    for (int i = threadIdx.x; i < n_int; i += blockDim.x) {
        int v = tm[i];
        if (v == 0x3F800000) atomicOr(&has_float, 1);
        else if (v != 0 && v != 1) atomicOr(&has_other, 1);
    }
    __syncthreads();
    if (threadIdx.x == 0) *flag = has_float ? 2 : (has_other ? 0 : 1);
}

// ---------------- CSR build ----------------
__global__ void hist_kernel(const int* __restrict__ dst, int e, int* __restrict__ counts) {
    int i = blockIdx.x * blockDim.x + threadIdx.x;
    if (i < e) atomicAdd(&counts[dst[i]], 1);
}

__global__ __launch_bounds__(1024) void scan_kernel(const int* __restrict__ counts,
                                                    int* __restrict__ offsets,
                                                    int* __restrict__ cursor, int n) {
    const int T = 1024;
    int tid = threadIdx.x;
    int items = (n + T - 1) / T;
    int beg = tid * items;
    int end = min(beg + items, n);
    int local = 0;
    for (int i = beg; i < end; ++i) local += counts[i];
    int lane = tid & 63, wid = tid >> 6;
    int incl = local;
    #pragma unroll
    for (int d = 1; d < 64; d <<= 1) {
        int u = __shfl_up(incl, d, 64);
        if (lane >= d) incl += u;
    }
    __shared__ int wsum[16];
    if (lane == 63) wsum[wid] = incl;
    __syncthreads();
    if (wid == 0 && lane < 16) {
        int v = wsum[lane];
        #pragma unroll
        for (int d = 1; d < 16; d <<= 1) {
            int u = __shfl_up(v, d, 64);
            if (lane >= d) v += u;
        }
        wsum[lane] = v;  // inclusive across waves
    }
    __syncthreads();
    int wave_off = (wid == 0) ? 0 : wsum[wid - 1];
    int run = wave_off + incl - local;  // exclusive prefix for this thread
    for (int i = beg; i < end; ++i) {
        offsets[i] = run;
        cursor[i] = run;
        run += counts[i];
    }
    if (tid == T - 1) offsets[n] = wave_off + incl;  // total
}

__global__ void scatter_kernel(const int* __restrict__ src, const int* __restrict__ dst, int e,
                               int* __restrict__ cursor, int* __restrict__ csr_src) {
    int i = blockIdx.x * blockDim.x + threadIdx.x;
    if (i < e) {
        int p = atomicAdd(&cursor[dst[i]], 1);
        csr_src[p] = src[i];
    }
}

// ---------------- mean aggregation: one wave per dst node ----------------
__global__ __launch_bounds__(256) void aggr_kernel(const float* __restrict__ h,
                                                   const int* __restrict__ offsets,
                                                   const int* __restrict__ csr,
                                                   float* __restrict__ out, int n) {
    int node = (int)((blockIdx.x * (size_t)blockDim.x + threadIdx.x) >> 6);
    int lane = threadIdx.x & 63;
    if (node >= n) return;
    int beg = offsets[node], end = offsets[node + 1];
    float2 acc = make_float2(0.f, 0.f);
    const float2* hp = (const float2*)h;
    for (int i = beg; i < end; ++i) {
        int s = csr[i];  // wave-uniform
        float2 v = hp[(size_t)s * 64 + lane];
        acc.x += v.x; acc.y += v.y;
    }
    float inv = 1.0f / (float)max(end - beg, 1);
    float2 r = make_float2(acc.x * inv, acc.y * inv);
    ((float2*)out)[(size_t)node * 64 + lane] = r;
}

// ---------------- layer 1: C = relu(A1@W1 + A2@W2 + bias), K=128 each, M=128 ----------------
__global__ __launch_bounds__(256) void gemm_relu_kernel(
    const float* __restrict__ A1, const float* __restrict__ A2,
    const float* __restrict__ W1, const float* __restrict__ W2,
    const float* __restrict__ bias, float* __restrict__ C, int n) {
    __shared__ float As[64][36];
    __shared__ float Ws[32][128];
    int t = threadIdx.x;
    int tx = t & 15, ty = t >> 4;
    int row0 = blockIdx.x * 64;
    float acc[4][8];
    #pragma unroll
    for (int i = 0; i < 4; ++i)
        #pragma unroll
        for (int j = 0; j < 8; ++j) acc[i][j] = 0.f;

    for (int half = 0; half < 2; ++half) {
        const float* A = half ? A2 : A1;
        const float* W = half ? W2 : W1;
        for (int kc = 0; kc < 4; ++kc) {
            // stage A tile 64x32
            #pragma unroll
            for (int i = 0; i < 2; ++i) {
                int idx = t + i * 256;
                int r = idx >> 3;
                int kq = (idx & 7) << 2;
                float4 v = make_float4(0.f, 0.f, 0.f, 0.f);
                int grow = row0 + r;
                if (grow < n) v = *(const float4*)&A[(size_t)grow * 128 + kc * 32 + kq];
                *(float4*)&As[r][kq] = v;
            }
            // stage W tile 32x128
            #pragma unroll
            for (int i = 0; i < 4; ++i) {
                int idx = t + i * 256;
                int kr = idx >> 5;
                int mq = (idx & 31) << 2;
                *(float4*)&Ws[kr][mq] = *(const float4*)&W[(size_t)(kc * 32 + kr) * 128 + mq];
            }
            __syncthreads();
            #pragma unroll
            for (int k = 0; k < 32; ++k) {
                float a0 = As[ty * 4 + 0][k];
                float a1 = As[ty * 4 + 1][k];
                float a2 = As[ty * 4 + 2][k];
                float a3 = As[ty * 4 + 3][k];
                float4 w0 = *(float4*)&Ws[k][tx * 8];
                float4 w1 = *(float4*)&Ws[k][tx * 8 + 4];
                float wv[8] = {w0.x, w0.y, w0.z, w0.w, w1.x, w1.y, w1.z, w1.w};
                float av[4] = {a0, a1, a2, a3};
                #pragma unroll
                for (int i = 0; i < 4; ++i)
                    #pragma unroll
                    for (int j = 0; j < 8; ++j) acc[i][j] = fmaf(av[i], wv[j], acc[i][j]);
            }
            __syncthreads();
        }
    }
    // epilogue
    float bv[8];
    #pragma unroll
    for (int j = 0; j < 8; ++j) bv[j] = bias[tx * 8 + j];
    #pragma unroll
    for (int i = 0; i < 4; ++i) {
        int grow = row0 + ty * 4 + i;
        if (grow >= n) continue;
        float4 o0, o1;
        o0.x = fmaxf(acc[i][0] + bv[0], 0.f);
        o0.y = fmaxf(acc[i][1] + bv[1], 0.f);
        o0.z = fmaxf(acc[i][2] + bv[2], 0.f);
        o0.w = fmaxf(acc[i][3] + bv[3], 0.f);
        o1.x = fmaxf(acc[i][4] + bv[4], 0.f);
        o1.y = fmaxf(acc[i][5] + bv[5], 0.f);
        o1.z = fmaxf(acc[i][6] + bv[6], 0.f);
        o1.w = fmaxf(acc[i][7] + bv[7], 0.f);
        *(float4*)&C[(size_t)grow * 128 + tx * 8] = o0;
        *(float4*)&C[(size_t)grow * 128 + tx * 8 + 4] = o1;
    }
}

// ---------------- layer 2 + log_softmax + masked NLL ----------------
__global__ __launch_bounds__(256) void gemm2_loss_kernel(
    const float* __restrict__ A1, const float* __restrict__ A2,
    const float* __restrict__ W1, const float* __restrict__ W2,
    const float* __restrict__ bias,
    const int* __restrict__ y, const void* __restrict__ tmask,
    const int* __restrict__ flag, float* __restrict__ accum, int n) {
    __shared__ float As[64][36];
    __shared__ float Ws[32][64];
    __shared__ float Ls[64][65];
    int t = threadIdx.x;
    int tx = t & 15, ty = t >> 4;
    int row0 = blockIdx.x * 64;
    float acc[4][4];
    #pragma unroll
    for (int i = 0; i < 4; ++i)
        #pragma unroll
        for (int j = 0; j < 4; ++j) acc[i][j] = 0.f;

    for (int half = 0; half < 2; ++half) {
        const float* A = half ? A2 : A1;
        const float* W = half ? W2 : W1;
        for (int kc = 0; kc < 4; ++kc) {
            #pragma unroll
            for (int i = 0; i < 2; ++i) {
                int idx = t + i * 256;
                int r = idx >> 3;
                int kq = (idx & 7) << 2;
                float4 v = make_float4(0.f, 0.f, 0.f, 0.f);
                int grow = row0 + r;
                if (grow < n) v = *(const float4*)&A[(size_t)grow * 128 + kc * 32 + kq];
                *(float4*)&As[r][kq] = v;
            }
            #pragma unroll
            for (int i = 0; i < 2; ++i) {
                int idx = t + i * 256;
                int kr = idx >> 4;
                int mq = (idx & 15) << 2;
                *(float4*)&Ws[kr][mq] = *(const float4*)&W[(size_t)(kc * 32 + kr) * 64 + mq];
            }
            __syncthreads();
            #pragma unroll
            for (int k = 0; k < 32; ++k) {
                float av[4];
                #pragma unroll
                for (int i = 0; i < 4; ++i) av[i] = As[ty * 4 + i][k];
                float4 w = *(float4*)&Ws[k][tx * 4];
                float wv[4] = {w.x, w.y, w.z, w.w};
                #pragma unroll
                for (int i = 0; i < 4; ++i)
                    #pragma unroll
                    for (int j = 0; j < 4; ++j) acc[i][j] = fmaf(av[i], wv[j], acc[i][j]);
            }
            __syncthreads();
        }
    }
    // logits into LDS
    #pragma unroll
    for (int i = 0; i < 4; ++i)
        #pragma unroll
        for (int j = 0; j < 4; ++j) Ls[ty * 4 + i][tx * 4 + j] = acc[i][j] + bias[tx * 4 + j];
    __syncthreads();
    // wave 0: one thread per row -> log_softmax + NLL
    if (t < 64) {
        int grow = row0 + t;
        float num = 0.f, den = 0.f;
        if (grow < n) {
            bool m;
            int f = *flag;
            if (f == 0)      m = ((const unsigned char*)tmask)[grow] != 0;
            else if (f == 1) m = ((const int*)tmask)[grow] != 0;
            else             m = ((const float*)tmask)[grow] != 0.f;
            if (m) {
                float mx = -1e30f;
                for (int j = 0; j < 64; ++j) mx = fmaxf(mx, Ls[t][j]);
                float s = 0.f;
                for (int j = 0; j < 64; ++j) s += expf(Ls[t][j] - mx);
                int cls = y[grow];
                float logp = Ls[t][cls] - mx - logf(s);
                num = -logp;
                den = 1.f;
            }
        }
        #pragma unroll
        for (int d = 32; d; d >>= 1) {
            num += __shfl_down(num, d, 64);
            den += __shfl_down(den, d, 64);
        }
        if (t == 0) {
            atomicAdd(&accum[0], num);
            atomicAdd(&accum[1], den);
        }
    }
}

__global__ void finalize_kernel(const float* __restrict__ accum, float* __restrict__ out) {
    out[0] = accum[0] / fmaxf(accum[1], 1.0f);
}

extern "C" void kernel_launch(void* const* d_in, const int* in_sizes, int n_in,
                              void* d_out, int out_size, void* d_ws, size_t ws_size,
                              hipStream_t stream) {
    const float* x        = (const float*)d_in[0];
    const int*   edge_src = (const int*)d_in[1];
    const int*   edge_dst = (const int*)d_in[2];
    const int*   y        = (const int*)d_in[3];
    const void*  tmask    = (const void*)d_in[4];
    const float* W1l      = (const float*)d_in[5];
    const float* b1       = (const float*)d_in[6];
    const float* W1r      = (const float*)d_in[7];
    const float* W2l      = (const float*)d_in[8];
    const float* b2       = (const float*)d_in[9];
    const float* W2r      = (const float*)d_in[10];

    const int N = in_sizes[0] / DIN;
    const int E = in_sizes[1];

    char* ws = (char*)d_ws;
    float* accum = (float*)ws;            // [num, den]
    int* flag    = (int*)(ws + 8);
    size_t off = 256;
    int* counts  = (int*)(ws + off); off += al256((size_t)N * 4);
    int* offsets = (int*)(ws + off); off += al256(((size_t)N + 1) * 4);
    int* cursor  = (int*)(ws + off); off += al256((size_t)N * 4);
    int* csr     = (int*)(ws + off); off += al256((size_t)E * 4);
    float* abuf  = (float*)(ws + off); off += al256((size_t)N * DIN * 4);
    float* h1    = (float*)(ws + off); off += al256((size_t)N * DHID * 4);

    hipMemsetAsync(ws, 0, 256, stream);
    hipMemsetAsync(counts, 0, (size_t)N * 4, stream);

    detect_mask_kernel<<<1, 256, 0, stream>>>((const int*)tmask, N / 4, flag);

    int eb = (E + 255) / 256;
    hist_kernel<<<eb, 256, 0, stream>>>(edge_dst, E, counts);
    scan_kernel<<<1, 1024, 0, stream>>>(counts, offsets, cursor, N);
    scatter_kernel<<<eb, 256, 0, stream>>>(edge_src, edge_dst, E, cursor, csr);

    int ab = (N + 3) / 4;  // 4 waves per block, 1 node per wave
    int gb = (N + 63) / 64;

    // layer 1
    aggr_kernel<<<ab, 256, 0, stream>>>(x, offsets, csr, abuf, N);
    gemm_relu_kernel<<<gb, 256, 0, stream>>>(abuf, x, W1l, W1r, b1, h1, N);
    // layer 2 + loss
    aggr_kernel<<<ab, 256, 0, stream>>>(h1, offsets, csr, abuf, N);
    gemm2_loss_kernel<<<gb, 256, 0, stream>>>(abuf, h1, W2l, W2r, b2, y, tmask, flag, accum, N);

    finalize_kernel<<<1, 1, 0, stream>>>(accum, (float*)d_out);
}

// Round 2
// 466.610 us; speedup vs baseline: 1.2129x; 1.2129x over previous
//
#include <hip/hip_runtime.h>
#include <hip/hip_bf16.h>

// Dims fixed by the problem
#define DIN 128
#define DHID 128
#define DOUT 64

static inline size_t al256(size_t x) { return (x + 255) & ~(size_t)255; }

// ---------------- mask encoding auto-detect ----------------
// train_mask is bool in the reference; harness may pass it as raw u8,
// int32, or float32. Detect from bit patterns: flag 0=u8, 1=int32, 2=f32.
__global__ void detect_mask_kernel(const int* __restrict__ tm, int n_int, int* __restrict__ flag) {
    __shared__ int has_float, has_other;
    if (threadIdx.x == 0) { has_float = 0; has_other = 0; }
    __syncthreads();
    for (int i = threadIdx.x; i < n_int; i += blockDim.x) {
        int v = tm[i];
        if (v == 0x3F800000) atomicOr(&has_float, 1);
        else if (v != 0 && v != 1) atomicOr(&has_other, 1);
    }
    __syncthreads();
    if (threadIdx.x == 0) *flag = has_float ? 2 : (has_other ? 0 : 1);
}

// ---------------- CSR build ----------------
__global__ void hist_kernel(const int* __restrict__ dst, int e, int* __restrict__ counts) {
    int i = blockIdx.x * blockDim.x + threadIdx.x;
    if (i < e) atomicAdd(&counts[dst[i]], 1);
}

// Multi-block scan, stage A: per-block (1024 items) sums
__global__ __launch_bounds__(256) void scan_partial_kernel(const int* __restrict__ counts, int n,
                                                           int* __restrict__ partials) {
    int t = threadIdx.x;
    int base = blockIdx.x * 1024 + t * 4;
    int s = 0;
    if (base + 3 < n) {
        int4 v = *(const int4*)&counts[base];
        s = v.x + v.y + v.z + v.w;
    } else {
        for (int i = 0; i < 4; ++i) if (base + i < n) s += counts[base + i];
    }
    #pragma unroll
    for (int d = 32; d; d >>= 1) s += __shfl_down(s, d, 64);
    __shared__ int wsum[4];
    if ((t & 63) == 0) wsum[t >> 6] = s;
    __syncthreads();
    if (t == 0) partials[blockIdx.x] = wsum[0] + wsum[1] + wsum[2] + wsum[3];
}

// Stage B: single-wave exclusive scan of partials (nparts <= 64), writes total to offsets[n]
__global__ void scan_top_kernel(int* __restrict__ partials, int nparts, int* __restrict__ total_out) {
    int lane = threadIdx.x;
    int v = (lane < nparts) ? partials[lane] : 0;
    int incl = v;
    #pragma unroll
    for (int d = 1; d < 64; d <<= 1) {
        int u = __shfl_up(incl, d, 64);
        if (lane >= d) incl += u;
    }
    if (lane < nparts) partials[lane] = incl - v;
    if (lane == 63) *total_out = incl;
}

// Stage C: per-block exclusive scan + block offset -> offsets & cursor
__global__ __launch_bounds__(256) void scan_final_kernel(const int* __restrict__ counts, int n,
                                                         const int* __restrict__ partials,
                                                         int* __restrict__ offsets,
                                                         int* __restrict__ cursor) {
    int t = threadIdx.x;
    int base = blockIdx.x * 1024 + t * 4;
    int v0 = 0, v1 = 0, v2 = 0, v3 = 0;
    if (base + 3 < n) {
        int4 q = *(const int4*)&counts[base];
        v0 = q.x; v1 = q.y; v2 = q.z; v3 = q.w;
    } else {
        if (base + 0 < n) v0 = counts[base + 0];
        if (base + 1 < n) v1 = counts[base + 1];
        if (base + 2 < n) v2 = counts[base + 2];
        if (base + 3 < n) v3 = counts[base + 3];
    }
    int s = v0 + v1 + v2 + v3;
    int lane = t & 63, wid = t >> 6;
    int incl = s;
    #pragma unroll
    for (int d = 1; d < 64; d <<= 1) {
        int u = __shfl_up(incl, d, 64);
        if (lane >= d) incl += u;
    }
    __shared__ int wsum[4];
    if (lane == 63) wsum[wid] = incl;
    __syncthreads();
    int woff = 0;
    #pragma unroll
    for (int i = 0; i < 4; ++i) if (i < wid) woff += wsum[i];
    int run = partials[blockIdx.x] + woff + incl - s;
    if (base + 0 < n) { offsets[base + 0] = run; cursor[base + 0] = run; run += v0; }
    if (base + 1 < n) { offsets[base + 1] = run; cursor[base + 1] = run; run += v1; }
    if (base + 2 < n) { offsets[base + 2] = run; cursor[base + 2] = run; run += v2; }
    if (base + 3 < n) { offsets[base + 3] = run; cursor[base + 3] = run; run += v3; }
}

__global__ void scatter_kernel(const int* __restrict__ src, const int* __restrict__ dst, int e,
                               int* __restrict__ cursor, int* __restrict__ csr_src) {
    int i = blockIdx.x * blockDim.x + threadIdx.x;
    if (i < e) {
        int p = atomicAdd(&cursor[dst[i]], 1);
        csr_src[p] = src[i];
    }
}

// ---------------- mean aggregation: one wave per dst node ----------------
__global__ __launch_bounds__(256) void aggr_kernel(const float* __restrict__ h,
                                                   const int* __restrict__ offsets,
                                                   const int* __restrict__ csr,
                                                   float* __restrict__ out, int n) {
    int node = (int)((blockIdx.x * (size_t)blockDim.x + threadIdx.x) >> 6);
    int lane = threadIdx.x & 63;
    if (node >= n) return;
    int beg = offsets[node], end = offsets[node + 1];
    float2 acc = make_float2(0.f, 0.f);
    const float2* hp = (const float2*)h;
    for (int i = beg; i < end; ++i) {
        int s = csr[i];  // wave-uniform
        float2 v = hp[(size_t)s * 64 + lane];
        acc.x += v.x; acc.y += v.y;
    }
    float inv = 1.0f / (float)max(end - beg, 1);
    float2 r = make_float2(acc.x * inv, acc.y * inv);
    ((float2*)out)[(size_t)node * 64 + lane] = r;
}

// ---------------- layer 1: C = relu(A1@W1 + A2@W2 + bias), K=128 each, M=128 ----------------
__global__ __launch_bounds__(256) void gemm_relu_kernel(
    const float* __restrict__ A1, const float* __restrict__ A2,
    const float* __restrict__ W1, const float* __restrict__ W2,
    const float* __restrict__ bias, float* __restrict__ C, int n) {
    __shared__ float As[64][36];
    __shared__ float Ws[32][128];
    int t = threadIdx.x;
    int tx = t & 15, ty = t >> 4;
    int row0 = blockIdx.x * 64;
    float acc[4][8];
    #pragma unroll
    for (int i = 0; i < 4; ++i)
        #pragma unroll
        for (int j = 0; j < 8; ++j) acc[i][j] = 0.f;

    for (int half = 0; half < 2; ++half) {
        const float* A = half ? A2 : A1;
        const float* W = half ? W2 : W1;
        for (int kc = 0; kc < 4; ++kc) {
            // stage A tile 64x32
            #pragma unroll
            for (int i = 0; i < 2; ++i) {
                int idx = t + i * 256;
                int r = idx >> 3;
                int kq = (idx & 7) << 2;
                float4 v = make_float4(0.f, 0.f, 0.f, 0.f);
                int grow = row0 + r;
                if (grow < n) v = *(const float4*)&A[(size_t)grow * 128 + kc * 32 + kq];
                *(float4*)&As[r][kq] = v;
            }
            // stage W tile 32x128
            #pragma unroll
            for (int i = 0; i < 4; ++i) {
                int idx = t + i * 256;
                int kr = idx >> 5;
                int mq = (idx & 31) << 2;
                *(float4*)&Ws[kr][mq] = *(const float4*)&W[(size_t)(kc * 32 + kr) * 128 + mq];
            }
            __syncthreads();
            #pragma unroll
            for (int k = 0; k < 32; ++k) {
                float a0 = As[ty * 4 + 0][k];
                float a1 = As[ty * 4 + 1][k];
                float a2 = As[ty * 4 + 2][k];
                float a3 = As[ty * 4 + 3][k];
                float4 w0 = *(float4*)&Ws[k][tx * 8];
                float4 w1 = *(float4*)&Ws[k][tx * 8 + 4];
                float wv[8] = {w0.x, w0.y, w0.z, w0.w, w1.x, w1.y, w1.z, w1.w};
                float av[4] = {a0, a1, a2, a3};
                #pragma unroll
                for (int i = 0; i < 4; ++i)
                    #pragma unroll
                    for (int j = 0; j < 8; ++j) acc[i][j] = fmaf(av[i], wv[j], acc[i][j]);
            }
            __syncthreads();
        }
    }
    // epilogue
    float bv[8];
    #pragma unroll
    for (int j = 0; j < 8; ++j) bv[j] = bias[tx * 8 + j];
    #pragma unroll
    for (int i = 0; i < 4; ++i) {
        int grow = row0 + ty * 4 + i;
        if (grow >= n) continue;
        float4 o0, o1;
        o0.x = fmaxf(acc[i][0] + bv[0], 0.f);
        o0.y = fmaxf(acc[i][1] + bv[1], 0.f);
        o0.z = fmaxf(acc[i][2] + bv[2], 0.f);
        o0.w = fmaxf(acc[i][3] + bv[3], 0.f);
        o1.x = fmaxf(acc[i][4] + bv[4], 0.f);
        o1.y = fmaxf(acc[i][5] + bv[5], 0.f);
        o1.z = fmaxf(acc[i][6] + bv[6], 0.f);
        o1.w = fmaxf(acc[i][7] + bv[7], 0.f);
        *(float4*)&C[(size_t)grow * 128 + tx * 8] = o0;
        *(float4*)&C[(size_t)grow * 128 + tx * 8 + 4] = o1;
    }
}

// ---------------- layer 2 + log_softmax + masked NLL ----------------
__global__ __launch_bounds__(256) void gemm2_loss_kernel(
    const float* __restrict__ A1, const float* __restrict__ A2,
    const float* __restrict__ W1, const float* __restrict__ W2,
    const float* __restrict__ bias,
    const int* __restrict__ y, const void* __restrict__ tmask,
    const int* __restrict__ flag, float* __restrict__ accum, int n) {
    __shared__ float As[64][36];
    __shared__ float Ws[32][64];
    __shared__ float Ls[64][65];
    int t = threadIdx.x;
    int tx = t & 15, ty = t >> 4;
    int row0 = blockIdx.x * 64;
    float acc[4][4];
    #pragma unroll
    for (int i = 0; i < 4; ++i)
        #pragma unroll
        for (int j = 0; j < 4; ++j) acc[i][j] = 0.f;

    for (int half = 0; half < 2; ++half) {
        const float* A = half ? A2 : A1;
        const float* W = half ? W2 : W1;
        for (int kc = 0; kc < 4; ++kc) {
            #pragma unroll
            for (int i = 0; i < 2; ++i) {
                int idx = t + i * 256;
                int r = idx >> 3;
                int kq = (idx & 7) << 2;
                float4 v = make_float4(0.f, 0.f, 0.f, 0.f);
                int grow = row0 + r;
                if (grow < n) v = *(const float4*)&A[(size_t)grow * 128 + kc * 32 + kq];
                *(float4*)&As[r][kq] = v;
            }
            #pragma unroll
            for (int i = 0; i < 2; ++i) {
                int idx = t + i * 256;
                int kr = idx >> 4;
                int mq = (idx & 15) << 2;
                *(float4*)&Ws[kr][mq] = *(const float4*)&W[(size_t)(kc * 32 + kr) * 64 + mq];
            }
            __syncthreads();
            #pragma unroll
            for (int k = 0; k < 32; ++k) {
                float av[4];
                #pragma unroll
                for (int i = 0; i < 4; ++i) av[i] = As[ty * 4 + i][k];
                float4 w = *(float4*)&Ws[k][tx * 4];
                float wv[4] = {w.x, w.y, w.z, w.w};
                #pragma unroll
                for (int i = 0; i < 4; ++i)
                    #pragma unroll
                    for (int j = 0; j < 4; ++j) acc[i][j] = fmaf(av[i], wv[j], acc[i][j]);
            }
            __syncthreads();
        }
    }
    // logits into LDS
    #pragma unroll
    for (int i = 0; i < 4; ++i)
        #pragma unroll
        for (int j = 0; j < 4; ++j) Ls[ty * 4 + i][tx * 4 + j] = acc[i][j] + bias[tx * 4 + j];
    __syncthreads();
    // wave 0: one thread per row -> log_softmax + NLL
    if (t < 64) {
        int grow = row0 + t;
        float num = 0.f, den = 0.f;
        if (grow < n) {
            bool m;
            int f = *flag;
            if (f == 0)      m = ((const unsigned char*)tmask)[grow] != 0;
            else if (f == 1) m = ((const int*)tmask)[grow] != 0;
            else             m = ((const float*)tmask)[grow] != 0.f;
            if (m) {
                float mx = -1e30f;
                for (int j = 0; j < 64; ++j) mx = fmaxf(mx, Ls[t][j]);
                float s = 0.f;
                for (int j = 0; j < 64; ++j) s += expf(Ls[t][j] - mx);
                int cls = y[grow];
                float logp = Ls[t][cls] - mx - logf(s);
                num = -logp;
                den = 1.f;
            }
        }
        #pragma unroll
        for (int d = 32; d; d >>= 1) {
            num += __shfl_down(num, d, 64);
            den += __shfl_down(den, d, 64);
        }
        if (t == 0) {
            atomicAdd(&accum[0], num);
            atomicAdd(&accum[1], den);
        }
    }
}

__global__ void finalize_kernel(const float* __restrict__ accum, float* __restrict__ out) {
    out[0] = accum[0] / fmaxf(accum[1], 1.0f);
}

extern "C" void kernel_launch(void* const* d_in, const int* in_sizes, int n_in,
                              void* d_out, int out_size, void* d_ws, size_t ws_size,
                              hipStream_t stream) {
    const float* x        = (const float*)d_in[0];
    const int*   edge_src = (const int*)d_in[1];
    const int*   edge_dst = (const int*)d_in[2];
    const int*   y        = (const int*)d_in[3];
    const void*  tmask    = (const void*)d_in[4];
    const float* W1l      = (const float*)d_in[5];
    const float* b1       = (const float*)d_in[6];
    const float* W1r      = (const float*)d_in[7];
    const float* W2l      = (const float*)d_in[8];
    const float* b2       = (const float*)d_in[9];
    const float* W2r      = (const float*)d_in[10];

    const int N = in_sizes[0] / DIN;
    const int E = in_sizes[1];

    char* ws = (char*)d_ws;
    float* accum = (float*)ws;            // [num, den]
    int* flag    = (int*)(ws + 8);
    size_t off = 256;
    int* counts   = (int*)(ws + off); off += al256((size_t)N * 4);
    int* offsets  = (int*)(ws + off); off += al256(((size_t)N + 1) * 4);
    int* cursor   = (int*)(ws + off); off += al256((size_t)N * 4);
    int* csr      = (int*)(ws + off); off += al256((size_t)E * 4);
    int* partials = (int*)(ws + off); off += al256(64 * 4);
    float* abuf   = (float*)(ws + off); off += al256((size_t)N * DIN * 4);
    float* h1     = (float*)(ws + off); off += al256((size_t)N * DHID * 4);

    hipMemsetAsync(ws, 0, 256, stream);
    hipMemsetAsync(counts, 0, (size_t)N * 4, stream);

    detect_mask_kernel<<<1, 256, 0, stream>>>((const int*)tmask, N / 4, flag);

    int eb = (E + 255) / 256;
    hist_kernel<<<eb, 256, 0, stream>>>(edge_dst, E, counts);

    int sb = (N + 1023) / 1024;  // 49 blocks for N=50000
    scan_partial_kernel<<<sb, 256, 0, stream>>>(counts, N, partials);
    scan_top_kernel<<<1, 64, 0, stream>>>(partials, sb, &offsets[N]);
    scan_final_kernel<<<sb, 256, 0, stream>>>(counts, N, partials, offsets, cursor);

    scatter_kernel<<<eb, 256, 0, stream>>>(edge_src, edge_dst, E, cursor, csr);

    int ab = (N + 3) / 4;  // 4 waves per block, 1 node per wave
    int gb = (N + 63) / 64;

    // layer 1
    aggr_kernel<<<ab, 256, 0, stream>>>(x, offsets, csr, abuf, N);
    gemm_relu_kernel<<<gb, 256, 0, stream>>>(abuf, x, W1l, W1r, b1, h1, N);
    // layer 2 + loss
    aggr_kernel<<<ab, 256, 0, stream>>>(h1, offsets, csr, abuf, N);
    gemm2_loss_kernel<<<gb, 256, 0, stream>>>(abuf, h1, W2l, W2r, b2, y, tmask, flag, accum, N);

    finalize_kernel<<<1, 1, 0, stream>>>(accum, (float*)d_out);
}

// Round 3
// 346.117 us; speedup vs baseline: 1.6351x; 1.3481x over previous
//
#include <hip/hip_runtime.h>
#include <hip/hip_bf16.h>

typedef unsigned int uint;

// Dims fixed by the problem
#define DIN 128
#define DHID 128
#define DOUT 64

static inline size_t al256(size_t x) { return (x + 255) & ~(size_t)255; }

// bf16 pair helpers (uint = two bf16, low bits = even feature)
__device__ inline float2 bf2x(uint v) {
    return make_float2(__uint_as_float(v << 16), __uint_as_float(v & 0xffff0000u));
}
__device__ inline uint packbf(float a, float b) {
    uint ua = __float_as_uint(a), ub = __float_as_uint(b);
    ua += 0x7fff + ((ua >> 16) & 1);   // RNE
    ub += 0x7fff + ((ub >> 16) & 1);
    return (ua >> 16) | (ub & 0xffff0000u);
}

// ---------------- mask encoding auto-detect ----------------
// gflags[0]=saw float 1.0f pattern, gflags[1]=saw non-{0,1} word (u8 packing)
__global__ void detect_mask_kernel(const int* __restrict__ tm, int n_int, int* __restrict__ gflags) {
    int i = blockIdx.x * blockDim.x + threadIdx.x;
    bool hf = false, ho = false;
    for (; i < n_int; i += gridDim.x * blockDim.x) {
        int v = tm[i];
        hf |= (v == 0x3F800000);
        ho |= (v != 0 && v != 1 && v != 0x3F800000);
    }
    if (__any(hf) && (threadIdx.x & 63) == 0) atomicOr(&gflags[0], 1);
    if (__any(ho) && (threadIdx.x & 63) == 0) atomicOr(&gflags[1], 1);
}

// ---------------- CSR build ----------------
__global__ void hist_kernel(const int* __restrict__ dst, int e, int* __restrict__ counts) {
    int i = blockIdx.x * blockDim.x + threadIdx.x;
    if (i < e) atomicAdd(&counts[dst[i]], 1);
}

__global__ __launch_bounds__(256) void scan_partial_kernel(const int* __restrict__ counts, int n,
                                                           int* __restrict__ partials) {
    int t = threadIdx.x;
    int base = blockIdx.x * 1024 + t * 4;
    int s = 0;
    if (base + 3 < n) {
        int4 v = *(const int4*)&counts[base];
        s = v.x + v.y + v.z + v.w;
    } else {
        for (int i = 0; i < 4; ++i) if (base + i < n) s += counts[base + i];
    }
    #pragma unroll
    for (int d = 32; d; d >>= 1) s += __shfl_down(s, d, 64);
    __shared__ int wsum[4];
    if ((t & 63) == 0) wsum[t >> 6] = s;
    __syncthreads();
    if (t == 0) partials[blockIdx.x] = wsum[0] + wsum[1] + wsum[2] + wsum[3];
}

__global__ void scan_top_kernel(int* __restrict__ partials, int nparts, int* __restrict__ total_out) {
    int lane = threadIdx.x;
    int v = (lane < nparts) ? partials[lane] : 0;
    int incl = v;
    #pragma unroll
    for (int d = 1; d < 64; d <<= 1) {
        int u = __shfl_up(incl, d, 64);
        if (lane >= d) incl += u;
    }
    if (lane < nparts) partials[lane] = incl - v;
    if (lane == 63) *total_out = incl;
}

__global__ __launch_bounds__(256) void scan_final_kernel(const int* __restrict__ counts, int n,
                                                         const int* __restrict__ partials,
                                                         int* __restrict__ offsets,
                                                         int* __restrict__ cursor) {
    int t = threadIdx.x;
    int base = blockIdx.x * 1024 + t * 4;
    int v0 = 0, v1 = 0, v2 = 0, v3 = 0;
    if (base + 3 < n) {
        int4 q = *(const int4*)&counts[base];
        v0 = q.x; v1 = q.y; v2 = q.z; v3 = q.w;
    } else {
        if (base + 0 < n) v0 = counts[base + 0];
        if (base + 1 < n) v1 = counts[base + 1];
        if (base + 2 < n) v2 = counts[base + 2];
        if (base + 3 < n) v3 = counts[base + 3];
    }
    int s = v0 + v1 + v2 + v3;
    int lane = t & 63, wid = t >> 6;
    int incl = s;
    #pragma unroll
    for (int d = 1; d < 64; d <<= 1) {
        int u = __shfl_up(incl, d, 64);
        if (lane >= d) incl += u;
    }
    __shared__ int wsum[4];
    if (lane == 63) wsum[wid] = incl;
    __syncthreads();
    int woff = 0;
    #pragma unroll
    for (int i = 0; i < 4; ++i) if (i < wid) woff += wsum[i];
    int run = partials[blockIdx.x] + woff + incl - s;
    if (base + 0 < n) { offsets[base + 0] = run; cursor[base + 0] = run; run += v0; }
    if (base + 1 < n) { offsets[base + 1] = run; cursor[base + 1] = run; run += v1; }
    if (base + 2 < n) { offsets[base + 2] = run; cursor[base + 2] = run; run += v2; }
    if (base + 3 < n) { offsets[base + 3] = run; cursor[base + 3] = run; run += v3; }
}

__global__ void scatter_kernel(const int* __restrict__ src, const int* __restrict__ dst, int e,
                               int* __restrict__ cursor, int* __restrict__ csr_src) {
    int i = blockIdx.x * blockDim.x + threadIdx.x;
    if (i < e) {
        int p = atomicAdd(&cursor[dst[i]], 1);
        csr_src[p] = src[i];
    }
}

// ---------------- gemm1: P1 = x@W1l (bf16), Q1 = x@W1r + b1 (f32) ----------------
__global__ __launch_bounds__(256) void gemm1_kernel(
    const float* __restrict__ X,
    const float* __restrict__ W1lg, const float* __restrict__ W1rg,
    const float* __restrict__ b1,
    uint* __restrict__ P1u, float* __restrict__ Q1, int n) {
    __shared__ float As[64][36];
    __shared__ float Wl[32][128];
    __shared__ float Wr[32][128];
    int t = threadIdx.x;
    int tx = t & 15, ty = t >> 4;
    int row0 = blockIdx.x * 64;
    float acc1[4][8], acc2[4][8];
    #pragma unroll
    for (int i = 0; i < 4; ++i)
        #pragma unroll
        for (int j = 0; j < 8; ++j) { acc1[i][j] = 0.f; acc2[i][j] = 0.f; }

    for (int kc = 0; kc < 4; ++kc) {
        #pragma unroll
        for (int i = 0; i < 2; ++i) {
            int idx = t + i * 256;
            int r = idx >> 3, kq = (idx & 7) << 2;
            float4 v = make_float4(0.f, 0.f, 0.f, 0.f);
            int grow = row0 + r;
            if (grow < n) v = *(const float4*)&X[(size_t)grow * 128 + kc * 32 + kq];
            *(float4*)&As[r][kq] = v;
        }
        #pragma unroll
        for (int i = 0; i < 4; ++i) {
            int idx = t + i * 256;
            int kr = idx >> 5, mq = (idx & 31) << 2;
            *(float4*)&Wl[kr][mq] = *(const float4*)&W1lg[(size_t)(kc * 32 + kr) * 128 + mq];
            *(float4*)&Wr[kr][mq] = *(const float4*)&W1rg[(size_t)(kc * 32 + kr) * 128 + mq];
        }
        __syncthreads();
        #pragma unroll
        for (int k = 0; k < 32; ++k) {
            float av[4];
            #pragma unroll
            for (int i = 0; i < 4; ++i) av[i] = As[ty * 4 + i][k];
            float4 wl0 = *(float4*)&Wl[k][tx * 8];
            float4 wl1 = *(float4*)&Wl[k][tx * 8 + 4];
            float4 wr0 = *(float4*)&Wr[k][tx * 8];
            float4 wr1 = *(float4*)&Wr[k][tx * 8 + 4];
            float wlv[8] = {wl0.x, wl0.y, wl0.z, wl0.w, wl1.x, wl1.y, wl1.z, wl1.w};
            float wrv[8] = {wr0.x, wr0.y, wr0.z, wr0.w, wr1.x, wr1.y, wr1.z, wr1.w};
            #pragma unroll
            for (int i = 0; i < 4; ++i)
                #pragma unroll
                for (int j = 0; j < 8; ++j) {
                    acc1[i][j] = fmaf(av[i], wlv[j], acc1[i][j]);
                    acc2[i][j] = fmaf(av[i], wrv[j], acc2[i][j]);
                }
        }
        __syncthreads();
    }
    float bv[8];
    #pragma unroll
    for (int j = 0; j < 8; ++j) bv[j] = b1[tx * 8 + j];
    #pragma unroll
    for (int i = 0; i < 4; ++i) {
        int grow = row0 + ty * 4 + i;
        if (grow >= n) continue;
        uint4 p;
        p.x = packbf(acc1[i][0], acc1[i][1]);
        p.y = packbf(acc1[i][2], acc1[i][3]);
        p.z = packbf(acc1[i][4], acc1[i][5]);
        p.w = packbf(acc1[i][6], acc1[i][7]);
        *(uint4*)&P1u[(size_t)grow * 64 + tx * 4] = p;
        float4 q0 = make_float4(acc2[i][0] + bv[0], acc2[i][1] + bv[1], acc2[i][2] + bv[2], acc2[i][3] + bv[3]);
        float4 q1 = make_float4(acc2[i][4] + bv[4], acc2[i][5] + bv[5], acc2[i][6] + bv[6], acc2[i][7] + bv[7]);
        *(float4*)&Q1[(size_t)grow * 128 + tx * 8] = q0;
        *(float4*)&Q1[(size_t)grow * 128 + tx * 8 + 4] = q1;
    }
}

// ---------------- aggr1: h1 = relu(mean(P1) + Q1) -> bf16 ----------------
__global__ __launch_bounds__(256) void aggr1_kernel(
    const uint* __restrict__ P1u, const float* __restrict__ Q1,
    const int* __restrict__ offsets, const int* __restrict__ csr,
    uint* __restrict__ h1u, int n) {
    int node = (int)((blockIdx.x * (size_t)blockDim.x + threadIdx.x) >> 6);
    int lane = threadIdx.x & 63;
    if (node >= n) return;
    int beg = offsets[node], end = offsets[node + 1];
    float ax = 0.f, ay = 0.f;
    int i = beg;
    for (; i + 4 <= end; i += 4) {
        int s0 = csr[i], s1 = csr[i + 1], s2 = csr[i + 2], s3 = csr[i + 3];
        uint v0 = P1u[(size_t)s0 * 64 + lane];
        uint v1 = P1u[(size_t)s1 * 64 + lane];
        uint v2 = P1u[(size_t)s2 * 64 + lane];
        uint v3 = P1u[(size_t)s3 * 64 + lane];
        float2 a0 = bf2x(v0), a1 = bf2x(v1), a2 = bf2x(v2), a3 = bf2x(v3);
        ax += (a0.x + a1.x) + (a2.x + a3.x);
        ay += (a0.y + a1.y) + (a2.y + a3.y);
    }
    for (; i < end; ++i) {
        int s = csr[i];
        float2 a = bf2x(P1u[(size_t)s * 64 + lane]);
        ax += a.x; ay += a.y;
    }
    float inv = 1.0f / (float)max(end - beg, 1);
    float2 q = ((const float2*)Q1)[(size_t)node * 64 + lane];
    float rx = fmaxf(fmaf(ax, inv, q.x), 0.f);
    float ry = fmaxf(fmaf(ay, inv, q.y), 0.f);
    h1u[(size_t)node * 64 + lane] = packbf(rx, ry);
}

// ---------------- gemm2: P2 = h1@W2l (bf16), Q2 = h1@W2r + b2 (f32) ----------------
__global__ __launch_bounds__(256) void gemm2_kernel(
    const uint* __restrict__ H1u,
    const float* __restrict__ W2lg, const float* __restrict__ W2rg,
    const float* __restrict__ b2,
    uint* __restrict__ P2u, float* __restrict__ Q2, int n) {
    __shared__ float As[64][36];
    __shared__ float Wl[32][64];
    __shared__ float Wr[32][64];
    int t = threadIdx.x;
    int tx = t & 15, ty = t >> 4;
    int row0 = blockIdx.x * 64;
    float acc1[4][4], acc2[4][4];
    #pragma unroll
    for (int i = 0; i < 4; ++i)
        #pragma unroll
        for (int j = 0; j < 4; ++j) { acc1[i][j] = 0.f; acc2[i][j] = 0.f; }

    for (int kc = 0; kc < 4; ++kc) {
        {
            int r = t >> 2, c = t & 3;
            uint4 v = make_uint4(0u, 0u, 0u, 0u);
            int grow = row0 + r;
            if (grow < n) v = *(const uint4*)&H1u[(size_t)grow * 64 + kc * 16 + c * 4];
            int f0 = c * 8;
            float2 e;
            e = bf2x(v.x); As[r][f0 + 0] = e.x; As[r][f0 + 1] = e.y;
            e = bf2x(v.y); As[r][f0 + 2] = e.x; As[r][f0 + 3] = e.y;
            e = bf2x(v.z); As[r][f0 + 4] = e.x; As[r][f0 + 5] = e.y;
            e = bf2x(v.w); As[r][f0 + 6] = e.x; As[r][f0 + 7] = e.y;
        }
        #pragma unroll
        for (int i = 0; i < 2; ++i) {
            int idx = t + i * 256;
            int kr = idx >> 4, mq = (idx & 15) << 2;
            *(float4*)&Wl[kr][mq] = *(const float4*)&W2lg[(size_t)(kc * 32 + kr) * 64 + mq];
            *(float4*)&Wr[kr][mq] = *(const float4*)&W2rg[(size_t)(kc * 32 + kr) * 64 + mq];
        }
        __syncthreads();
        #pragma unroll
        for (int k = 0; k < 32; ++k) {
            float av[4];
            #pragma unroll
            for (int i = 0; i < 4; ++i) av[i] = As[ty * 4 + i][k];
            float4 wl = *(float4*)&Wl[k][tx * 4];
            float4 wr = *(float4*)&Wr[k][tx * 4];
            float wlv[4] = {wl.x, wl.y, wl.z, wl.w};
            float wrv[4] = {wr.x, wr.y, wr.z, wr.w};
            #pragma unroll
            for (int i = 0; i < 4; ++i)
                #pragma unroll
                for (int j = 0; j < 4; ++j) {
                    acc1[i][j] = fmaf(av[i], wlv[j], acc1[i][j]);
                    acc2[i][j] = fmaf(av[i], wrv[j], acc2[i][j]);
                }
        }
        __syncthreads();
    }
    float bv[4];
    #pragma unroll
    for (int j = 0; j < 4; ++j) bv[j] = b2[tx * 4 + j];
    #pragma unroll
    for (int i = 0; i < 4; ++i) {
        int grow = row0 + ty * 4 + i;
        if (grow >= n) continue;
        uint2 p;
        p.x = packbf(acc1[i][0], acc1[i][1]);
        p.y = packbf(acc1[i][2], acc1[i][3]);
        *(uint2*)&P2u[(size_t)grow * 32 + tx * 2] = p;
        float4 q = make_float4(acc2[i][0] + bv[0], acc2[i][1] + bv[1], acc2[i][2] + bv[2], acc2[i][3] + bv[3]);
        *(float4*)&Q2[(size_t)grow * 64 + tx * 4] = q;
    }
}

// ---------------- loss: logits = mean(P2) + Q2 ; log_softmax ; masked NLL ----------------
// 1024 threads = 16 waves = 16 nodes/block. Half-wave per edge (2 edges in flight).
__global__ __launch_bounds__(1024) void loss_kernel(
    const uint* __restrict__ P2u, const float* __restrict__ Q2,
    const int* __restrict__ offsets, const int* __restrict__ csr,
    const int* __restrict__ y, const void* __restrict__ tmask,
    const int* __restrict__ gflags, float2* __restrict__ bpart, int n) {
    int wid = threadIdx.x >> 6;
    int node = blockIdx.x * 16 + wid;
    int lane = threadIdx.x & 63;
    int l = lane & 31, hw = lane >> 5;
    float num = 0.f, den = 0.f;
    if (node < n) {
        int beg = offsets[node], end = offsets[node + 1];
        float ax = 0.f, ay = 0.f;
        int i = beg + hw;
        for (; i + 2 < end; i += 4) {
            int s0 = csr[i], s1 = csr[i + 2];
            uint v0 = P2u[(size_t)s0 * 32 + l];
            uint v1 = P2u[(size_t)s1 * 32 + l];
            float2 a0 = bf2x(v0), a1 = bf2x(v1);
            ax += a0.x + a1.x; ay += a0.y + a1.y;
        }
        for (; i < end; i += 2) {
            int s = csr[i];
            float2 a = bf2x(P2u[(size_t)s * 32 + l]);
            ax += a.x; ay += a.y;
        }
        ax += __shfl_xor(ax, 32, 64);
        ay += __shfl_xor(ay, 32, 64);
        float inv = 1.0f / (float)max(end - beg, 1);
        float2 q = ((const float2*)Q2)[(size_t)node * 32 + l];
        float Lx = fmaf(ax, inv, q.x);
        float Ly = fmaf(ay, inv, q.y);
        float mx = fmaxf(Lx, Ly);
        #pragma unroll
        for (int d = 16; d; d >>= 1) mx = fmaxf(mx, __shfl_xor(mx, d, 64));
        float s = __expf(Lx - mx) + __expf(Ly - mx);
        #pragma unroll
        for (int d = 16; d; d >>= 1) s += __shfl_xor(s, d, 64);
        int cls = y[node];
        float Lxc = __shfl(Lx, (cls >> 1) & 31, 64);
        float Lyc = __shfl(Ly, (cls >> 1) & 31, 64);
        float Lc = (cls & 1) ? Lyc : Lxc;
        float logp = (Lc - mx) - __logf(s);
        int f = gflags[0] ? 2 : (gflags[1] ? 0 : 1);
        bool m;
        if (f == 0)      m = ((const unsigned char*)tmask)[node] != 0;
        else if (f == 1) m = ((const int*)tmask)[node] != 0;
        else             m = ((const float*)tmask)[node] != 0.f;
        if (m) { num = -logp; den = 1.f; }
    }
    __shared__ float2 wacc[16];
    if (lane == 0) wacc[wid] = make_float2(num, den);
    __syncthreads();
    if (threadIdx.x == 0) {
        float rx = 0.f, ry = 0.f;
        #pragma unroll
        for (int i = 0; i < 16; ++i) { rx += wacc[i].x; ry += wacc[i].y; }
        bpart[blockIdx.x] = make_float2(rx, ry);
    }
}

__global__ __launch_bounds__(1024) void finalize_kernel(const float2* __restrict__ bpart, int nb,
                                                        float* __restrict__ out) {
    int t = threadIdx.x;
    float sx = 0.f, sy = 0.f;
    for (int i = t; i < nb; i += 1024) { float2 v = bpart[i]; sx += v.x; sy += v.y; }
    #pragma unroll
    for (int d = 32; d; d >>= 1) { sx += __shfl_down(sx, d, 64); sy += __shfl_down(sy, d, 64); }
    __shared__ float2 wacc[16];
    if ((t & 63) == 0) wacc[t >> 6] = make_float2(sx, sy);
    __syncthreads();
    if (t == 0) {
        float nx = 0.f, ny = 0.f;
        #pragma unroll
        for (int i = 0; i < 16; ++i) { nx += wacc[i].x; ny += wacc[i].y; }
        out[0] = nx / fmaxf(ny, 1.f);
    }
}

extern "C" void kernel_launch(void* const* d_in, const int* in_sizes, int n_in,
                              void* d_out, int out_size, void* d_ws, size_t ws_size,
                              hipStream_t stream) {
    const float* x        = (const float*)d_in[0];
    const int*   edge_src = (const int*)d_in[1];
    const int*   edge_dst = (const int*)d_in[2];
    const int*   y        = (const int*)d_in[3];
    const void*  tmask    = (const void*)d_in[4];
    const float* W1l      = (const float*)d_in[5];
    const float* b1       = (const float*)d_in[6];
    const float* W1r      = (const float*)d_in[7];
    const float* W2l      = (const float*)d_in[8];
    const float* b2       = (const float*)d_in[9];
    const float* W2r      = (const float*)d_in[10];

    const int N = in_sizes[0] / DIN;
    const int E = in_sizes[1];
    const int nb_loss = (N + 15) / 16;

    char* ws = (char*)d_ws;
    int* gflags = (int*)ws;  // 2 ints
    size_t off = 256;
    int* counts   = (int*)(ws + off); off += al256((size_t)N * 4);
    int* offsets  = (int*)(ws + off); off += al256(((size_t)N + 1) * 4);
    int* cursor   = (int*)(ws + off); off += al256((size_t)N * 4);
    int* csr      = (int*)(ws + off); off += al256((size_t)E * 4);
    int* spart    = (int*)(ws + off); off += al256(64 * 4);
    float2* bpart = (float2*)(ws + off); off += al256((size_t)nb_loss * 8);
    uint* P1u     = (uint*)(ws + off); off += al256((size_t)N * 64 * 4);   // 12.8 MB
    uint* h1u     = (uint*)(ws + off); off += al256((size_t)N * 64 * 4);   // 12.8 MB
    float* Q1     = (float*)(ws + off); off += al256((size_t)N * 128 * 4); // 25.6 MB
    // P2/Q2 overlay the dead Q1 region (Q1 last read by aggr1, before gemm2)
    uint* P2u     = (uint*)Q1;                        // 6.4 MB
    float* Q2     = (float*)((char*)Q1 + al256((size_t)N * 32 * 4)); // 12.8 MB

    hipMemsetAsync(ws, 0, 256, stream);
    hipMemsetAsync(counts, 0, (size_t)N * 4, stream);

    detect_mask_kernel<<<64, 256, 0, stream>>>((const int*)tmask, N / 4, gflags);

    int eb = (E + 255) / 256;
    hist_kernel<<<eb, 256, 0, stream>>>(edge_dst, E, counts);

    int sb = (N + 1023) / 1024;
    scan_partial_kernel<<<sb, 256, 0, stream>>>(counts, N, spart);
    scan_top_kernel<<<1, 64, 0, stream>>>(spart, sb, &offsets[N]);
    scan_final_kernel<<<sb, 256, 0, stream>>>(counts, N, spart, offsets, cursor);

    scatter_kernel<<<eb, 256, 0, stream>>>(edge_src, edge_dst, E, cursor, csr);

    int gb = (N + 63) / 64;
    int ab = (N + 3) / 4;

    // layer 1: transform-then-aggregate (mean_aggr(x)@W = mean_aggr(x@W))
    gemm1_kernel<<<gb, 256, 0, stream>>>(x, W1l, W1r, b1, P1u, Q1, N);
    aggr1_kernel<<<ab, 256, 0, stream>>>(P1u, Q1, offsets, csr, h1u, N);
    // layer 2
    gemm2_kernel<<<gb, 256, 0, stream>>>(h1u, W2l, W2r, b2, P2u, Q2, N);
    loss_kernel<<<nb_loss, 1024, 0, stream>>>(P2u, Q2, offsets, csr, y, tmask, gflags, bpart, N);

    finalize_kernel<<<1, 1024, 0, stream>>>(bpart, nb_loss, (float*)d_out);
}

// Round 4
// 302.085 us; speedup vs baseline: 1.8735x; 1.1458x over previous
//
#include <hip/hip_runtime.h>
#include <hip/hip_bf16.h>

typedef unsigned int uint;
typedef unsigned short u16;

// Dims fixed by the problem
#define DIN 128
#define DHID 128
#define DOUT 64

static inline size_t al256(size_t x) { return (x + 255) & ~(size_t)255; }

typedef __attribute__((ext_vector_type(8))) short short8;
typedef __attribute__((ext_vector_type(4))) float floatx4;

// bf16 pair helpers (uint = two bf16, low bits = even feature)
__device__ inline float2 bf2x(uint v) {
    return make_float2(__uint_as_float(v << 16), __uint_as_float(v & 0xffff0000u));
}
__device__ inline uint packbf(float a, float b) {
    uint ua = __float_as_uint(a), ub = __float_as_uint(b);
    ua += 0x7fff + ((ua >> 16) & 1);   // RNE
    ub += 0x7fff + ((ub >> 16) & 1);
    return (ua >> 16) | (ub & 0xffff0000u);
}
__device__ inline u16 pb(float a) {
    uint u = __float_as_uint(a);
    u += 0x7fff + ((u >> 16) & 1);
    return (u16)(u >> 16);
}

// ---------------- mask encoding auto-detect ----------------
__global__ void detect_mask_kernel(const int* __restrict__ tm, int n_int, int* __restrict__ gflags) {
    int i = blockIdx.x * blockDim.x + threadIdx.x;
    bool hf = false, ho = false;
    for (; i < n_int; i += gridDim.x * blockDim.x) {
        int v = tm[i];
        hf |= (v == 0x3F800000);
        ho |= (v != 0 && v != 1 && v != 0x3F800000);
    }
    if (__any(hf) && (threadIdx.x & 63) == 0) atomicOr(&gflags[0], 1);
    if (__any(ho) && (threadIdx.x & 63) == 0) atomicOr(&gflags[1], 1);
}

// ---------------- CSR build ----------------
__global__ void hist_kernel(const int* __restrict__ dst, int e, int* __restrict__ counts) {
    int i = blockIdx.x * blockDim.x + threadIdx.x;
    if (i < e) atomicAdd(&counts[dst[i]], 1);
}

__global__ __launch_bounds__(256) void scan_partial_kernel(const int* __restrict__ counts, int n,
                                                           int* __restrict__ partials) {
    int t = threadIdx.x;
    int base = blockIdx.x * 1024 + t * 4;
    int s = 0;
    if (base + 3 < n) {
        int4 v = *(const int4*)&counts[base];
        s = v.x + v.y + v.z + v.w;
    } else {
        for (int i = 0; i < 4; ++i) if (base + i < n) s += counts[base + i];
    }
    #pragma unroll
    for (int d = 32; d; d >>= 1) s += __shfl_down(s, d, 64);
    __shared__ int wsum[4];
    if ((t & 63) == 0) wsum[t >> 6] = s;
    __syncthreads();
    if (t == 0) partials[blockIdx.x] = wsum[0] + wsum[1] + wsum[2] + wsum[3];
}

__global__ void scan_top_kernel(int* __restrict__ partials, int nparts, int* __restrict__ total_out) {
    int lane = threadIdx.x;
    int v = (lane < nparts) ? partials[lane] : 0;
    int incl = v;
    #pragma unroll
    for (int d = 1; d < 64; d <<= 1) {
        int u = __shfl_up(incl, d, 64);
        if (lane >= d) incl += u;
    }
    if (lane < nparts) partials[lane] = incl - v;
    if (lane == 63) *total_out = incl;
}

__global__ __launch_bounds__(256) void scan_final_kernel(const int* __restrict__ counts, int n,
                                                         const int* __restrict__ partials,
                                                         int* __restrict__ offsets,
                                                         int* __restrict__ cursor) {
    int t = threadIdx.x;
    int base = blockIdx.x * 1024 + t * 4;
    int v0 = 0, v1 = 0, v2 = 0, v3 = 0;
    if (base + 3 < n) {
        int4 q = *(const int4*)&counts[base];
        v0 = q.x; v1 = q.y; v2 = q.z; v3 = q.w;
    } else {
        if (base + 0 < n) v0 = counts[base + 0];
        if (base + 1 < n) v1 = counts[base + 1];
        if (base + 2 < n) v2 = counts[base + 2];
        if (base + 3 < n) v3 = counts[base + 3];
    }
    int s = v0 + v1 + v2 + v3;
    int lane = t & 63, wid = t >> 6;
    int incl = s;
    #pragma unroll
    for (int d = 1; d < 64; d <<= 1) {
        int u = __shfl_up(incl, d, 64);
        if (lane >= d) incl += u;
    }
    __shared__ int wsum[4];
    if (lane == 63) wsum[wid] = incl;
    __syncthreads();
    int woff = 0;
    #pragma unroll
    for (int i = 0; i < 4; ++i) if (i < wid) woff += wsum[i];
    int run = partials[blockIdx.x] + woff + incl - s;
    if (base + 0 < n) { offsets[base + 0] = run; cursor[base + 0] = run; run += v0; }
    if (base + 1 < n) { offsets[base + 1] = run; cursor[base + 1] = run; run += v1; }
    if (base + 2 < n) { offsets[base + 2] = run; cursor[base + 2] = run; run += v2; }
    if (base + 3 < n) { offsets[base + 3] = run; cursor[base + 3] = run; run += v3; }
}

__global__ void scatter_kernel(const int* __restrict__ src, const int* __restrict__ dst, int e,
                               int* __restrict__ cursor, int* __restrict__ csr_src) {
    int i = blockIdx.x * blockDim.x + threadIdx.x;
    if (i < e) {
        int p = atomicAdd(&cursor[dst[i]], 1);
        csr_src[p] = src[i];
    }
}

// ---------------- W pre-pack into MFMA B-fragment order (bf16) ----------------
// B-frag layout for mfma_f32_16x16x32_bf16: lane holds B[k=(lane>>4)*8+j][n=lane&15], j=0..7.
// Wp1: concat [W1l | W1r] -> 256 cols, frag_id = kc*16+tn, elem = lane*8+j.
// Wp2: concat [W2l | W2r] -> 128 cols, frag_id = kc*8+tn.
__global__ void pack_w_kernel(const float* __restrict__ W1l, const float* __restrict__ W1r,
                              const float* __restrict__ W2l, const float* __restrict__ W2r,
                              u16* __restrict__ Wp1, u16* __restrict__ Wp2) {
    int id = blockIdx.x * 256 + threadIdx.x;
    if (id < 32768) {
        int frag = id >> 9, e = id & 511;
        int lane = e >> 3, j = e & 7;
        int kc = frag >> 4, tn = frag & 15;
        int k = kc * 32 + (lane >> 4) * 8 + j;
        int ncol = tn * 16 + (lane & 15);
        float v = (ncol < 128) ? W1l[k * 128 + ncol] : W1r[k * 128 + ncol - 128];
        Wp1[id] = pb(v);
    } else if (id < 49152) {
        int id2 = id - 32768;
        int frag = id2 >> 9, e = id2 & 511;
        int lane = e >> 3, j = e & 7;
        int kc = frag >> 3, tn = frag & 7;
        int k = kc * 32 + (lane >> 4) * 8 + j;
        int ncol = tn * 16 + (lane & 15);
        float v = (ncol < 64) ? W2l[k * 64 + ncol] : W2r[k * 64 + ncol - 64];
        Wp2[id2] = pb(v);
    }
}

// ---------------- gemm1 (MFMA): P1 = bf16(x@W1l), Q1 = bf16(x@W1r + b1) ----------------
// Wave = 16 rows x 256 cols. A-frags direct from global (fp32 -> bf16 inline).
__global__ __launch_bounds__(256) void gemm1_mfma(
    const float* __restrict__ X, const u16* __restrict__ Wp1,
    const float* __restrict__ b1,
    uint* __restrict__ P1u, uint* __restrict__ Q1u, int n) {
    __shared__ u16 ep[4][16][260];
    int t = threadIdx.x;
    int w = t >> 6, lane = t & 63;
    int q = lane >> 4, c = lane & 15;
    int m0 = blockIdx.x * 64 + w * 16;
    int me = min(m0 + c, n - 1);
    const float* xrow = X + (size_t)me * 128 + q * 8;
    const u16* wbase = Wp1 + lane * 8;

    floatx4 acc[16];
    #pragma unroll
    for (int i = 0; i < 16; ++i) acc[i] = (floatx4){0.f, 0.f, 0.f, 0.f};

    #pragma unroll
    for (int kc = 0; kc < 4; ++kc) {
        float4 x0 = *(const float4*)(xrow + kc * 32);
        float4 x1 = *(const float4*)(xrow + kc * 32 + 4);
        union { short8 s; uint4 u; } a;
        a.u.x = packbf(x0.x, x0.y); a.u.y = packbf(x0.z, x0.w);
        a.u.z = packbf(x1.x, x1.y); a.u.w = packbf(x1.z, x1.w);
        #pragma unroll
        for (int tn = 0; tn < 16; ++tn) {
            union { short8 s; uint4 u; } b;
            b.u = *(const uint4*)(wbase + (kc * 16 + tn) * 512);
            acc[tn] = __builtin_amdgcn_mfma_f32_16x16x32_bf16(a.s, b.s, acc[tn], 0, 0, 0);
        }
    }

    // epilogue: C/D layout col=lane&15, row=(lane>>4)*4+reg -> LDS transpose -> coalesced stores
    #pragma unroll
    for (int tn = 0; tn < 16; ++tn) {
        int col = tn * 16 + c;
        float badd = (tn >= 8) ? b1[col - 128] : 0.f;
        #pragma unroll
        for (int i = 0; i < 4; ++i)
            ep[w][q * 4 + i][col] = pb(acc[tn][i] + badd);
    }
    for (int r = 0; r < 16; ++r) {
        int grow = m0 + r;
        if (grow >= n) break;
        uint2 v = *(const uint2*)&ep[w][r][lane * 4];
        uint* dst = (lane < 32) ? (P1u + (size_t)grow * 64 + 2 * lane)
                                : (Q1u + (size_t)grow * 64 + 2 * (lane - 32));
        *(uint2*)dst = v;
    }
}

// ---------------- aggr1: h1 = bf16(relu(mean(P1) + Q1)) ----------------
__global__ __launch_bounds__(256) void aggr1_kernel(
    const uint* __restrict__ P1u, const uint* __restrict__ Q1u,
    const int* __restrict__ offsets, const int* __restrict__ csr,
    uint* __restrict__ h1u, int n) {
    int node = (int)((blockIdx.x * (size_t)blockDim.x + threadIdx.x) >> 6);
    int lane = threadIdx.x & 63;
    if (node >= n) return;
    int beg = offsets[node], end = offsets[node + 1];
    float ax = 0.f, ay = 0.f;
    int i = beg;
    for (; i + 4 <= end; i += 4) {
        int s0 = csr[i], s1 = csr[i + 1], s2 = csr[i + 2], s3 = csr[i + 3];
        uint v0 = P1u[(size_t)s0 * 64 + lane];
        uint v1 = P1u[(size_t)s1 * 64 + lane];
        uint v2 = P1u[(size_t)s2 * 64 + lane];
        uint v3 = P1u[(size_t)s3 * 64 + lane];
        float2 a0 = bf2x(v0), a1 = bf2x(v1), a2 = bf2x(v2), a3 = bf2x(v3);
        ax += (a0.x + a1.x) + (a2.x + a3.x);
        ay += (a0.y + a1.y) + (a2.y + a3.y);
    }
    for (; i < end; ++i) {
        int s = csr[i];
        float2 a = bf2x(P1u[(size_t)s * 64 + lane]);
        ax += a.x; ay += a.y;
    }
    float inv = 1.0f / (float)max(end - beg, 1);
    float2 qv = bf2x(Q1u[(size_t)node * 64 + lane]);
    float rx = fmaxf(fmaf(ax, inv, qv.x), 0.f);
    float ry = fmaxf(fmaf(ay, inv, qv.y), 0.f);
    h1u[(size_t)node * 64 + lane] = packbf(rx, ry);
}

// ---------------- gemm2 (MFMA): P2 = bf16(h1@W2l), Q2 = bf16(h1@W2r + b2) ----------------
__global__ __launch_bounds__(256) void gemm2_mfma(
    const uint* __restrict__ H1u, const u16* __restrict__ Wp2,
    const float* __restrict__ b2,
    uint* __restrict__ P2u, uint* __restrict__ Q2u, int n) {
    __shared__ u16 ep[4][16][132];
    int t = threadIdx.x;
    int w = t >> 6, lane = t & 63;
    int q = lane >> 4, c = lane & 15;
    int m0 = blockIdx.x * 64 + w * 16;
    int me = min(m0 + c, n - 1);
    const u16* hrow = (const u16*)H1u + (size_t)me * 128 + q * 8;
    const u16* wbase = Wp2 + lane * 8;

    floatx4 acc[8];
    #pragma unroll
    for (int i = 0; i < 8; ++i) acc[i] = (floatx4){0.f, 0.f, 0.f, 0.f};

    #pragma unroll
    for (int kc = 0; kc < 4; ++kc) {
        union { short8 s; uint4 u; } a;
        a.u = *(const uint4*)(hrow + kc * 32);
        #pragma unroll
        for (int tn = 0; tn < 8; ++tn) {
            union { short8 s; uint4 u; } b;
            b.u = *(const uint4*)(wbase + (kc * 8 + tn) * 512);
            acc[tn] = __builtin_amdgcn_mfma_f32_16x16x32_bf16(a.s, b.s, acc[tn], 0, 0, 0);
        }
    }

    #pragma unroll
    for (int tn = 0; tn < 8; ++tn) {
        int col = tn * 16 + c;
        float badd = (tn >= 4) ? b2[col - 64] : 0.f;
        #pragma unroll
        for (int i = 0; i < 4; ++i)
            ep[w][q * 4 + i][col] = pb(acc[tn][i] + badd);
    }
    for (int r = 0; r < 16; ++r) {
        int grow = m0 + r;
        if (grow >= n) break;
        uint v = *(const uint*)&ep[w][r][lane * 2];
        uint* dst = (lane < 32) ? (P2u + (size_t)grow * 32 + lane)
                                : (Q2u + (size_t)grow * 32 + (lane - 32));
        *dst = v;
    }
}

// ---------------- loss: logits = mean(P2) + Q2 ; log_softmax ; masked NLL ----------------
__global__ __launch_bounds__(1024) void loss_kernel(
    const uint* __restrict__ P2u, const uint* __restrict__ Q2u,
    const int* __restrict__ offsets, const int* __restrict__ csr,
    const int* __restrict__ y, const void* __restrict__ tmask,
    const int* __restrict__ gflags, float2* __restrict__ bpart, int n) {
    int wid = threadIdx.x >> 6;
    int node = blockIdx.x * 16 + wid;
    int lane = threadIdx.x & 63;
    int l = lane & 31, hw = lane >> 5;
    float num = 0.f, den = 0.f;
    if (node < n) {
        int beg = offsets[node], end = offsets[node + 1];
        float ax = 0.f, ay = 0.f;
        int i = beg + hw;
        for (; i + 2 < end; i += 4) {
            int s0 = csr[i], s1 = csr[i + 2];
            uint v0 = P2u[(size_t)s0 * 32 + l];
            uint v1 = P2u[(size_t)s1 * 32 + l];
            float2 a0 = bf2x(v0), a1 = bf2x(v1);
            ax += a0.x + a1.x; ay += a0.y + a1.y;
        }
        for (; i < end; i += 2) {
            int s = csr[i];
            float2 a = bf2x(P2u[(size_t)s * 32 + l]);
            ax += a.x; ay += a.y;
        }
        ax += __shfl_xor(ax, 32, 64);
        ay += __shfl_xor(ay, 32, 64);
        float inv = 1.0f / (float)max(end - beg, 1);
        float2 qv = bf2x(Q2u[(size_t)node * 32 + l]);
        float Lx = fmaf(ax, inv, qv.x);
        float Ly = fmaf(ay, inv, qv.y);
        float mx = fmaxf(Lx, Ly);
        #pragma unroll
        for (int d = 16; d; d >>= 1) mx = fmaxf(mx, __shfl_xor(mx, d, 64));
        float s = __expf(Lx - mx) + __expf(Ly - mx);
        #pragma unroll
        for (int d = 16; d; d >>= 1) s += __shfl_xor(s, d, 64);
        int cls = y[node];
        float Lxc = __shfl(Lx, (cls >> 1) & 31, 64);
        float Lyc = __shfl(Ly, (cls >> 1) & 31, 64);
        float Lc = (cls & 1) ? Lyc : Lxc;
        float logp = (Lc - mx) - __logf(s);
        int f = gflags[0] ? 2 : (gflags[1] ? 0 : 1);
        bool m;
        if (f == 0)      m = ((const unsigned char*)tmask)[node] != 0;
        else if (f == 1) m = ((const int*)tmask)[node] != 0;
        else             m = ((const float*)tmask)[node] != 0.f;
        if (m) { num = -logp; den = 1.f; }
    }
    __shared__ float2 wacc[16];
    if (lane == 0) wacc[wid] = make_float2(num, den);
    __syncthreads();
    if (threadIdx.x == 0) {
        float rx = 0.f, ry = 0.f;
        #pragma unroll
        for (int i = 0; i < 16; ++i) { rx += wacc[i].x; ry += wacc[i].y; }
        bpart[blockIdx.x] = make_float2(rx, ry);
    }
}

__global__ __launch_bounds__(1024) void finalize_kernel(const float2* __restrict__ bpart, int nb,
                                                        float* __restrict__ out) {
    int t = threadIdx.x;
    float sx = 0.f, sy = 0.f;
    for (int i = t; i < nb; i += 1024) { float2 v = bpart[i]; sx += v.x; sy += v.y; }
    #pragma unroll
    for (int d = 32; d; d >>= 1) { sx += __shfl_down(sx, d, 64); sy += __shfl_down(sy, d, 64); }
    __shared__ float2 wacc[16];
    if ((t & 63) == 0) wacc[t >> 6] = make_float2(sx, sy);
    __syncthreads();
    if (t == 0) {
        float nx = 0.f, ny = 0.f;
        #pragma unroll
        for (int i = 0; i < 16; ++i) { nx += wacc[i].x; ny += wacc[i].y; }
        out[0] = nx / fmaxf(ny, 1.f);
    }
}

extern "C" void kernel_launch(void* const* d_in, const int* in_sizes, int n_in,
                              void* d_out, int out_size, void* d_ws, size_t ws_size,
                              hipStream_t stream) {
    const float* x        = (const float*)d_in[0];
    const int*   edge_src = (const int*)d_in[1];
    const int*   edge_dst = (const int*)d_in[2];
    const int*   y        = (const int*)d_in[3];
    const void*  tmask    = (const void*)d_in[4];
    const float* W1l      = (const float*)d_in[5];
    const float* b1       = (const float*)d_in[6];
    const float* W1r      = (const float*)d_in[7];
    const float* W2l      = (const float*)d_in[8];
    const float* b2       = (const float*)d_in[9];
    const float* W2r      = (const float*)d_in[10];

    const int N = in_sizes[0] / DIN;
    const int E = in_sizes[1];
    const int nb_loss = (N + 15) / 16;

    char* ws = (char*)d_ws;
    int* gflags = (int*)ws;  // 2 ints
    size_t off = 256;
    int* counts   = (int*)(ws + off); off += al256((size_t)N * 4);
    int* offsets  = (int*)(ws + off); off += al256(((size_t)N + 1) * 4);
    int* cursor   = (int*)(ws + off); off += al256((size_t)N * 4);
    int* csr      = (int*)(ws + off); off += al256((size_t)E * 4);
    int* spart    = (int*)(ws + off); off += al256(64 * 4);
    float2* bpart = (float2*)(ws + off); off += al256((size_t)nb_loss * 8);
    u16* Wp1      = (u16*)(ws + off); off += al256(32768 * 2);
    u16* Wp2      = (u16*)(ws + off); off += al256(16384 * 2);
    uint* P1u     = (uint*)(ws + off); off += al256((size_t)N * 64 * 4);   // 12.8 MB
    uint* h1u     = (uint*)(ws + off); off += al256((size_t)N * 64 * 4);   // 12.8 MB
    uint* Q1u     = (uint*)(ws + off); off += al256((size_t)N * 64 * 4);   // 12.8 MB
    // P2/Q2 overlay the dead Q1 region (Q1 last read by aggr1, before gemm2)
    uint* P2u     = Q1u;                      // N*32 uints
    uint* Q2u     = Q1u + (size_t)N * 32;     // N*32 uints

    hipMemsetAsync(ws, 0, 256, stream);
    hipMemsetAsync(counts, 0, (size_t)N * 4, stream);

    pack_w_kernel<<<192, 256, 0, stream>>>(W1l, W1r, W2l, W2r, Wp1, Wp2);
    detect_mask_kernel<<<64, 256, 0, stream>>>((const int*)tmask, N / 4, gflags);

    int eb = (E + 255) / 256;
    hist_kernel<<<eb, 256, 0, stream>>>(edge_dst, E, counts);

    int sb = (N + 1023) / 1024;
    scan_partial_kernel<<<sb, 256, 0, stream>>>(counts, N, spart);
    scan_top_kernel<<<1, 64, 0, stream>>>(spart, sb, &offsets[N]);
    scan_final_kernel<<<sb, 256, 0, stream>>>(counts, N, spart, offsets, cursor);

    scatter_kernel<<<eb, 256, 0, stream>>>(edge_src, edge_dst, E, cursor, csr);

    int gb = (N + 63) / 64;
    int ab = (N + 3) / 4;

    // layer 1: transform-then-aggregate (mean_aggr(x)@W = mean_aggr(x@W))
    gemm1_mfma<<<gb, 256, 0, stream>>>(x, Wp1, b1, P1u, Q1u, N);
    aggr1_kernel<<<ab, 256, 0, stream>>>(P1u, Q1u, offsets, csr, h1u, N);
    // layer 2
    gemm2_mfma<<<gb, 256, 0, stream>>>(h1u, Wp2, b2, P2u, Q2u, N);
    loss_kernel<<<nb_loss, 1024, 0, stream>>>(P2u, Q2u, offsets, csr, y, tmask, gflags, bpart, N);

    finalize_kernel<<<1, 1024, 0, stream>>>(bpart, nb_loss, (float*)d_out);
}

// Round 6
// 288.566 us; speedup vs baseline: 1.9612x; 1.0468x over previous
//
#include <hip/hip_runtime.h>
#include <hip/hip_bf16.h>

typedef unsigned int uint;
typedef unsigned short u16;

// Dims fixed by the problem
#define DIN 128
#define DHID 128
#define DOUT 64

static inline size_t al256(size_t x) { return (x + 255) & ~(size_t)255; }

typedef __attribute__((ext_vector_type(8))) short short8;
typedef __attribute__((ext_vector_type(4))) float floatx4;
typedef __attribute__((ext_vector_type(4))) int intx4;   // clang vector for nontemporal builtins

// bf16 pair helpers (uint = two bf16, low bits = even feature)
__device__ inline float2 bf2x(uint v) {
    return make_float2(__uint_as_float(v << 16), __uint_as_float(v & 0xffff0000u));
}
__device__ inline uint packbf(float a, float b) {
    uint ua = __float_as_uint(a), ub = __float_as_uint(b);
    ua += 0x7fff + ((ua >> 16) & 1);   // RNE
    ub += 0x7fff + ((ub >> 16) & 1);
    return (ua >> 16) | (ub & 0xffff0000u);
}
__device__ inline u16 pb(float a) {
    uint u = __float_as_uint(a);
    u += 0x7fff + ((u >> 16) & 1);
    return (u16)(u >> 16);
}

// ---------------- mask encoding auto-detect ----------------
__global__ void detect_mask_kernel(const int* __restrict__ tm, int n_int, int* __restrict__ gflags) {
    int i = blockIdx.x * blockDim.x + threadIdx.x;
    bool hf = false, ho = false;
    for (; i < n_int; i += gridDim.x * blockDim.x) {
        int v = tm[i];
        hf |= (v == 0x3F800000);
        ho |= (v != 0 && v != 1 && v != 0x3F800000);
    }
    if (__any(hf) && (threadIdx.x & 63) == 0) atomicOr(&gflags[0], 1);
    if (__any(ho) && (threadIdx.x & 63) == 0) atomicOr(&gflags[1], 1);
}

// ---------------- CSR build ----------------
// 4 edges/thread, non-temporal intx4 reads (read-once stream; keep L2 for csr/cursor)
__global__ __launch_bounds__(256) void hist_kernel(const int* __restrict__ dst, int e,
                                                   int* __restrict__ counts) {
    int base = (blockIdx.x * 256 + threadIdx.x) * 4;
    if (base + 4 <= e) {
        intx4 d = __builtin_nontemporal_load((const intx4*)(dst + base));
        atomicAdd(&counts[d.x], 1);
        atomicAdd(&counts[d.y], 1);
        atomicAdd(&counts[d.z], 1);
        atomicAdd(&counts[d.w], 1);
    } else {
        for (int i = base; i < e; ++i) atomicAdd(&counts[dst[i]], 1);
    }
}

__global__ __launch_bounds__(256) void scan_partial_kernel(const int* __restrict__ counts, int n,
                                                           int* __restrict__ partials) {
    int t = threadIdx.x;
    int base = blockIdx.x * 1024 + t * 4;
    int s = 0;
    if (base + 3 < n) {
        int4 v = *(const int4*)&counts[base];
        s = v.x + v.y + v.z + v.w;
    } else {
        for (int i = 0; i < 4; ++i) if (base + i < n) s += counts[base + i];
    }
    #pragma unroll
    for (int d = 32; d; d >>= 1) s += __shfl_down(s, d, 64);
    __shared__ int wsum[4];
    if ((t & 63) == 0) wsum[t >> 6] = s;
    __syncthreads();
    if (t == 0) partials[blockIdx.x] = wsum[0] + wsum[1] + wsum[2] + wsum[3];
}

__global__ void scan_top_kernel(int* __restrict__ partials, int nparts, int* __restrict__ total_out) {
    int lane = threadIdx.x;
    int v = (lane < nparts) ? partials[lane] : 0;
    int incl = v;
    #pragma unroll
    for (int d = 1; d < 64; d <<= 1) {
        int u = __shfl_up(incl, d, 64);
        if (lane >= d) incl += u;
    }
    if (lane < nparts) partials[lane] = incl - v;
    if (lane == 63) *total_out = incl;
}

__global__ __launch_bounds__(256) void scan_final_kernel(const int* __restrict__ counts, int n,
                                                         const int* __restrict__ partials,
                                                         int* __restrict__ offsets,
                                                         int* __restrict__ cursor) {
    int t = threadIdx.x;
    int base = blockIdx.x * 1024 + t * 4;
    int v0 = 0, v1 = 0, v2 = 0, v3 = 0;
    if (base + 3 < n) {
        int4 q = *(const int4*)&counts[base];
        v0 = q.x; v1 = q.y; v2 = q.z; v3 = q.w;
    } else {
        if (base + 0 < n) v0 = counts[base + 0];
        if (base + 1 < n) v1 = counts[base + 1];
        if (base + 2 < n) v2 = counts[base + 2];
        if (base + 3 < n) v3 = counts[base + 3];
    }
    int s = v0 + v1 + v2 + v3;
    int lane = t & 63, wid = t >> 6;
    int incl = s;
    #pragma unroll
    for (int d = 1; d < 64; d <<= 1) {
        int u = __shfl_up(incl, d, 64);
        if (lane >= d) incl += u;
    }
    __shared__ int wsum[4];
    if (lane == 63) wsum[wid] = incl;
    __syncthreads();
    int woff = 0;
    #pragma unroll
    for (int i = 0; i < 4; ++i) if (i < wid) woff += wsum[i];
    int run = partials[blockIdx.x] + woff + incl - s;
    if (base + 0 < n) { offsets[base + 0] = run; cursor[base + 0] = run; run += v0; }
    if (base + 1 < n) { offsets[base + 1] = run; cursor[base + 1] = run; run += v1; }
    if (base + 2 < n) { offsets[base + 2] = run; cursor[base + 2] = run; run += v2; }
    if (base + 3 < n) { offsets[base + 3] = run; cursor[base + 3] = run; run += v3; }
}

template <typename IT>
__global__ __launch_bounds__(256) void scatter_kernel(const int* __restrict__ src,
                                                      const int* __restrict__ dst, int e,
                                                      int* __restrict__ cursor,
                                                      IT* __restrict__ csr_src) {
    int base = (blockIdx.x * 256 + threadIdx.x) * 4;
    if (base + 4 <= e) {
        intx4 s = __builtin_nontemporal_load((const intx4*)(src + base));
        intx4 d = __builtin_nontemporal_load((const intx4*)(dst + base));
        int p0 = atomicAdd(&cursor[d.x], 1);
        int p1 = atomicAdd(&cursor[d.y], 1);
        int p2 = atomicAdd(&cursor[d.z], 1);
        int p3 = atomicAdd(&cursor[d.w], 1);
        csr_src[p0] = (IT)s.x;
        csr_src[p1] = (IT)s.y;
        csr_src[p2] = (IT)s.z;
        csr_src[p3] = (IT)s.w;
    } else {
        for (int i = base; i < e; ++i) {
            int p = atomicAdd(&cursor[dst[i]], 1);
            csr_src[p] = (IT)src[i];
        }
    }
}

// ---------------- W pre-pack into MFMA B-fragment order (bf16) ----------------
__global__ void pack_w_kernel(const float* __restrict__ W1l, const float* __restrict__ W1r,
                              const float* __restrict__ W2l, const float* __restrict__ W2r,
                              u16* __restrict__ Wp1, u16* __restrict__ Wp2) {
    int id = blockIdx.x * 256 + threadIdx.x;
    if (id < 32768) {
        int frag = id >> 9, e = id & 511;
        int lane = e >> 3, j = e & 7;
        int kc = frag >> 4, tn = frag & 15;
        int k = kc * 32 + (lane >> 4) * 8 + j;
        int ncol = tn * 16 + (lane & 15);
        float v = (ncol < 128) ? W1l[k * 128 + ncol] : W1r[k * 128 + ncol - 128];
        Wp1[id] = pb(v);
    } else if (id < 49152) {
        int id2 = id - 32768;
        int frag = id2 >> 9, e = id2 & 511;
        int lane = e >> 3, j = e & 7;
        int kc = frag >> 3, tn = frag & 7;
        int k = kc * 32 + (lane >> 4) * 8 + j;
        int ncol = tn * 16 + (lane & 15);
        float v = (ncol < 64) ? W2l[k * 64 + ncol] : W2r[k * 64 + ncol - 64];
        Wp2[id2] = pb(v);
    }
}

// ---------------- gemm1 (MFMA): P1 = bf16(x@W1l), Q1 = bf16(x@W1r + b1) ----------------
__global__ __launch_bounds__(256) void gemm1_mfma(
    const float* __restrict__ X, const u16* __restrict__ Wp1,
    const float* __restrict__ b1,
    uint* __restrict__ P1u, uint* __restrict__ Q1u, int n) {
    __shared__ u16 ep[4][16][260];
    int t = threadIdx.x;
    int w = t >> 6, lane = t & 63;
    int q = lane >> 4, c = lane & 15;
    int m0 = blockIdx.x * 64 + w * 16;
    int me = min(m0 + c, n - 1);
    const float* xrow = X + (size_t)me * 128 + q * 8;
    const u16* wbase = Wp1 + lane * 8;

    floatx4 acc[16];
    #pragma unroll
    for (int i = 0; i < 16; ++i) acc[i] = (floatx4){0.f, 0.f, 0.f, 0.f};

    #pragma unroll
    for (int kc = 0; kc < 4; ++kc) {
        float4 x0 = *(const float4*)(xrow + kc * 32);
        float4 x1 = *(const float4*)(xrow + kc * 32 + 4);
        union { short8 s; uint4 u; } a;
        a.u.x = packbf(x0.x, x0.y); a.u.y = packbf(x0.z, x0.w);
        a.u.z = packbf(x1.x, x1.y); a.u.w = packbf(x1.z, x1.w);
        #pragma unroll
        for (int tn = 0; tn < 16; ++tn) {
            union { short8 s; uint4 u; } b;
            b.u = *(const uint4*)(wbase + (kc * 16 + tn) * 512);
            acc[tn] = __builtin_amdgcn_mfma_f32_16x16x32_bf16(a.s, b.s, acc[tn], 0, 0, 0);
        }
    }

    #pragma unroll
    for (int tn = 0; tn < 16; ++tn) {
        int col = tn * 16 + c;
        float badd = (tn >= 8) ? b1[col - 128] : 0.f;
        #pragma unroll
        for (int i = 0; i < 4; ++i)
            ep[w][q * 4 + i][col] = pb(acc[tn][i] + badd);
    }
    for (int r = 0; r < 16; ++r) {
        int grow = m0 + r;
        if (grow >= n) break;
        uint2 v = *(const uint2*)&ep[w][r][lane * 4];
        uint* dst = (lane < 32) ? (P1u + (size_t)grow * 64 + 2 * lane)
                                : (Q1u + (size_t)grow * 64 + 2 * (lane - 32));
        *(uint2*)dst = v;
    }
}

// ---------------- aggr1: h1 = bf16(relu(mean(P1) + Q1)) ----------------
template <typename IT>
__global__ __launch_bounds__(256) void aggr1_kernel(
    const uint* __restrict__ P1u, const uint* __restrict__ Q1u,
    const int* __restrict__ offsets, const IT* __restrict__ csr,
    uint* __restrict__ h1u, int n) {
    int node = (int)((blockIdx.x * (size_t)blockDim.x + threadIdx.x) >> 6);
    int lane = threadIdx.x & 63;
    if (node >= n) return;
    int beg = offsets[node], end = offsets[node + 1];
    float ax = 0.f, ay = 0.f;
    int i = beg;
    for (; i + 4 <= end; i += 4) {
        int s0 = csr[i], s1 = csr[i + 1], s2 = csr[i + 2], s3 = csr[i + 3];
        uint v0 = P1u[(size_t)s0 * 64 + lane];
        uint v1 = P1u[(size_t)s1 * 64 + lane];
        uint v2 = P1u[(size_t)s2 * 64 + lane];
        uint v3 = P1u[(size_t)s3 * 64 + lane];
        float2 a0 = bf2x(v0), a1 = bf2x(v1), a2 = bf2x(v2), a3 = bf2x(v3);
        ax += (a0.x + a1.x) + (a2.x + a3.x);
        ay += (a0.y + a1.y) + (a2.y + a3.y);
    }
    for (; i < end; ++i) {
        int s = csr[i];
        float2 a = bf2x(P1u[(size_t)s * 64 + lane]);
        ax += a.x; ay += a.y;
    }
    float inv = 1.0f / (float)max(end - beg, 1);
    float2 qv = bf2x(Q1u[(size_t)node * 64 + lane]);
    float rx = fmaxf(fmaf(ax, inv, qv.x), 0.f);
    float ry = fmaxf(fmaf(ay, inv, qv.y), 0.f);
    h1u[(size_t)node * 64 + lane] = packbf(rx, ry);
}

// ---------------- gemm2 (MFMA): P2 = bf16(h1@W2l), Q2 = bf16(h1@W2r + b2) ----------------
__global__ __launch_bounds__(256) void gemm2_mfma(
    const uint* __restrict__ H1u, const u16* __restrict__ Wp2,
    const float* __restrict__ b2,
    uint* __restrict__ P2u, uint* __restrict__ Q2u, int n) {
    __shared__ u16 ep[4][16][132];
    int t = threadIdx.x;
    int w = t >> 6, lane = t & 63;
    int q = lane >> 4, c = lane & 15;
    int m0 = blockIdx.x * 64 + w * 16;
    int me = min(m0 + c, n - 1);
    const u16* hrow = (const u16*)H1u + (size_t)me * 128 + q * 8;
    const u16* wbase = Wp2 + lane * 8;

    floatx4 acc[8];
    #pragma unroll
    for (int i = 0; i < 8; ++i) acc[i] = (floatx4){0.f, 0.f, 0.f, 0.f};

    #pragma unroll
    for (int kc = 0; kc < 4; ++kc) {
        union { short8 s; uint4 u; } a;
        a.u = *(const uint4*)(hrow + kc * 32);
        #pragma unroll
        for (int tn = 0; tn < 8; ++tn) {
            union { short8 s; uint4 u; } b;
            b.u = *(const uint4*)(wbase + (kc * 8 + tn) * 512);
            acc[tn] = __builtin_amdgcn_mfma_f32_16x16x32_bf16(a.s, b.s, acc[tn], 0, 0, 0);
        }
    }

    #pragma unroll
    for (int tn = 0; tn < 8; ++tn) {
        int col = tn * 16 + c;
        float badd = (tn >= 4) ? b2[col - 64] : 0.f;
        #pragma unroll
        for (int i = 0; i < 4; ++i)
            ep[w][q * 4 + i][col] = pb(acc[tn][i] + badd);
    }
    for (int r = 0; r < 16; ++r) {
        int grow = m0 + r;
        if (grow >= n) break;
        uint v = *(const uint*)&ep[w][r][lane * 2];
        uint* dst = (lane < 32) ? (P2u + (size_t)grow * 32 + lane)
                                : (Q2u + (size_t)grow * 32 + (lane - 32));
        *dst = v;
    }
}

// ---------------- loss: logits = mean(P2) + Q2 ; log_softmax ; masked NLL ----------------
template <typename IT>
__global__ __launch_bounds__(1024) void loss_kernel(
    const uint* __restrict__ P2u, const uint* __restrict__ Q2u,
    const int* __restrict__ offsets, const IT* __restrict__ csr,
    const int* __restrict__ y, const void* __restrict__ tmask,
    const int* __restrict__ gflags, float2* __restrict__ bpart, int n) {
    int wid = threadIdx.x >> 6;
    int node = blockIdx.x * 16 + wid;
    int lane = threadIdx.x & 63;
    int l = lane & 31, hw = lane >> 5;
    float num = 0.f, den = 0.f;
    if (node < n) {
        int beg = offsets[node], end = offsets[node + 1];
        float ax = 0.f, ay = 0.f;
        int i = beg + hw;
        for (; i + 2 < end; i += 4) {
            int s0 = csr[i], s1 = csr[i + 2];
            uint v0 = P2u[(size_t)s0 * 32 + l];
            uint v1 = P2u[(size_t)s1 * 32 + l];
            float2 a0 = bf2x(v0), a1 = bf2x(v1);
            ax += a0.x + a1.x; ay += a0.y + a1.y;
        }
        for (; i < end; i += 2) {
            int s = csr[i];
            float2 a = bf2x(P2u[(size_t)s * 32 + l]);
            ax += a.x; ay += a.y;
        }
        ax += __shfl_xor(ax, 32, 64);
        ay += __shfl_xor(ay, 32, 64);
        float inv = 1.0f / (float)max(end - beg, 1);
        float2 qv = bf2x(Q2u[(size_t)node * 32 + l]);
        float Lx = fmaf(ax, inv, qv.x);
        float Ly = fmaf(ay, inv, qv.y);
        float mx = fmaxf(Lx, Ly);
        #pragma unroll
        for (int d = 16; d; d >>= 1) mx = fmaxf(mx, __shfl_xor(mx, d, 64));
        float s = __expf(Lx - mx) + __expf(Ly - mx);
        #pragma unroll
        for (int d = 16; d; d >>= 1) s += __shfl_xor(s, d, 64);
        int cls = y[node];
        float Lxc = __shfl(Lx, (cls >> 1) & 31, 64);
        float Lyc = __shfl(Ly, (cls >> 1) & 31, 64);
        float Lc = (cls & 1) ? Lyc : Lxc;
        float logp = (Lc - mx) - __logf(s);
        int f = gflags[0] ? 2 : (gflags[1] ? 0 : 1);
        bool m;
        if (f == 0)      m = ((const unsigned char*)tmask)[node] != 0;
        else if (f == 1) m = ((const int*)tmask)[node] != 0;
        else             m = ((const float*)tmask)[node] != 0.f;
        if (m) { num = -logp; den = 1.f; }
    }
    __shared__ float2 wacc[16];
    if (lane == 0) wacc[wid] = make_float2(num, den);
    __syncthreads();
    if (threadIdx.x == 0) {
        float rx = 0.f, ry = 0.f;
        #pragma unroll
        for (int i = 0; i < 16; ++i) { rx += wacc[i].x; ry += wacc[i].y; }
        bpart[blockIdx.x] = make_float2(rx, ry);
    }
}

__global__ __launch_bounds__(1024) void finalize_kernel(const float2* __restrict__ bpart, int nb,
                                                        float* __restrict__ out) {
    int t = threadIdx.x;
    float sx = 0.f, sy = 0.f;
    for (int i = t; i < nb; i += 1024) { float2 v = bpart[i]; sx += v.x; sy += v.y; }
    #pragma unroll
    for (int d = 32; d; d >>= 1) { sx += __shfl_down(sx, d, 64); sy += __shfl_down(sy, d, 64); }
    __shared__ float2 wacc[16];
    if ((t & 63) == 0) wacc[t >> 6] = make_float2(sx, sy);
    __syncthreads();
    if (t == 0) {
        float nx = 0.f, ny = 0.f;
        #pragma unroll
        for (int i = 0; i < 16; ++i) { nx += wacc[i].x; ny += wacc[i].y; }
        out[0] = nx / fmaxf(ny, 1.f);
    }
}

extern "C" void kernel_launch(void* const* d_in, const int* in_sizes, int n_in,
                              void* d_out, int out_size, void* d_ws, size_t ws_size,
                              hipStream_t stream) {
    const float* x        = (const float*)d_in[0];
    const int*   edge_src = (const int*)d_in[1];
    const int*   edge_dst = (const int*)d_in[2];
    const int*   y        = (const int*)d_in[3];
    const void*  tmask    = (const void*)d_in[4];
    const float* W1l      = (const float*)d_in[5];
    const float* b1       = (const float*)d_in[6];
    const float* W1r      = (const float*)d_in[7];
    const float* W2l      = (const float*)d_in[8];
    const float* b2       = (const float*)d_in[9];
    const float* W2r      = (const float*)d_in[10];

    const int N = in_sizes[0] / DIN;
    const int E = in_sizes[1];
    const int nb_loss = (N + 15) / 16;
    const bool small_idx = (N <= 65535);

    char* ws = (char*)d_ws;
    int* gflags = (int*)ws;  // 2 ints
    size_t off = 256;
    int* counts   = (int*)(ws + off); off += al256((size_t)N * 4);
    int* offsets  = (int*)(ws + off); off += al256(((size_t)N + 1) * 4);
    int* cursor   = (int*)(ws + off); off += al256((size_t)N * 4);
    void* csr     = (void*)(ws + off); off += al256((size_t)E * 4);  // u16 uses half
    int* spart    = (int*)(ws + off); off += al256(64 * 4);
    float2* bpart = (float2*)(ws + off); off += al256((size_t)nb_loss * 8);
    u16* Wp1      = (u16*)(ws + off); off += al256(32768 * 2);
    u16* Wp2      = (u16*)(ws + off); off += al256(16384 * 2);
    uint* P1u     = (uint*)(ws + off); off += al256((size_t)N * 64 * 4);   // 12.8 MB
    uint* h1u     = (uint*)(ws + off); off += al256((size_t)N * 64 * 4);   // 12.8 MB
    uint* Q1u     = (uint*)(ws + off); off += al256((size_t)N * 64 * 4);   // 12.8 MB
    // P2/Q2 overlay the dead Q1 region (Q1 last read by aggr1, before gemm2)
    uint* P2u     = Q1u;                      // N*32 uints
    uint* Q2u     = Q1u + (size_t)N * 32;     // N*32 uints

    hipMemsetAsync(ws, 0, 256, stream);
    hipMemsetAsync(counts, 0, (size_t)N * 4, stream);

    pack_w_kernel<<<192, 256, 0, stream>>>(W1l, W1r, W2l, W2r, Wp1, Wp2);
    detect_mask_kernel<<<64, 256, 0, stream>>>((const int*)tmask, N / 4, gflags);

    int eb4 = (E + 1023) / 1024;  // 4 edges per thread
    hist_kernel<<<eb4, 256, 0, stream>>>(edge_dst, E, counts);

    int sb = (N + 1023) / 1024;
    scan_partial_kernel<<<sb, 256, 0, stream>>>(counts, N, spart);
    scan_top_kernel<<<1, 64, 0, stream>>>(spart, sb, &offsets[N]);
    scan_final_kernel<<<sb, 256, 0, stream>>>(counts, N, spart, offsets, cursor);

    if (small_idx)
        scatter_kernel<u16><<<eb4, 256, 0, stream>>>(edge_src, edge_dst, E, cursor, (u16*)csr);
    else
        scatter_kernel<uint><<<eb4, 256, 0, stream>>>(edge_src, edge_dst, E, cursor, (uint*)csr);

    int gb = (N + 63) / 64;
    int ab = (N + 3) / 4;

    // layer 1: transform-then-aggregate (mean_aggr(x)@W = mean_aggr(x@W))
    gemm1_mfma<<<gb, 256, 0, stream>>>(x, Wp1, b1, P1u, Q1u, N);
    if (small_idx)
        aggr1_kernel<u16><<<ab, 256, 0, stream>>>(P1u, Q1u, offsets, (const u16*)csr, h1u, N);
    else
        aggr1_kernel<uint><<<ab, 256, 0, stream>>>(P1u, Q1u, offsets, (const uint*)csr, h1u, N);
    // layer 2
    gemm2_mfma<<<gb, 256, 0, stream>>>(h1u, Wp2, b2, P2u, Q2u, N);
    if (small_idx)
        loss_kernel<u16><<<nb_loss, 1024, 0, stream>>>(P2u, Q2u, offsets, (const u16*)csr, y, tmask, gflags, bpart, N);
    else
        loss_kernel<uint><<<nb_loss, 1024, 0, stream>>>(P2u, Q2u, offsets, (const uint*)csr, y, tmask, gflags, bpart, N);

    finalize_kernel<<<1, 1024, 0, stream>>>(bpart, nb_loss, (float*)d_out);
}

// Round 7
// 281.255 us; speedup vs baseline: 2.0122x; 1.0260x over previous
//
#include <hip/hip_runtime.h>
#include <hip/hip_bf16.h>

typedef unsigned int uint;
typedef unsigned short u16;

// Dims fixed by the problem
#define DIN 128
#define DHID 128
#define DOUT 64

static inline size_t al256(size_t x) { return (x + 255) & ~(size_t)255; }

typedef __attribute__((ext_vector_type(8))) short short8;
typedef __attribute__((ext_vector_type(4))) float floatx4;
typedef __attribute__((ext_vector_type(2))) float floatx2;
typedef __attribute__((ext_vector_type(4))) int intx4;   // clang vector for nontemporal builtins

// bf16 pair helpers (uint = two bf16, low bits = even feature)
__device__ inline float2 bf2x(uint v) {
    return make_float2(__uint_as_float(v << 16), __uint_as_float(v & 0xffff0000u));
}
__device__ inline uint packbf(float a, float b) {
    uint ua = __float_as_uint(a), ub = __float_as_uint(b);
    ua += 0x7fff + ((ua >> 16) & 1);   // RNE
    ub += 0x7fff + ((ub >> 16) & 1);
    return (ua >> 16) | (ub & 0xffff0000u);
}
__device__ inline u16 pb(float a) {
    uint u = __float_as_uint(a);
    u += 0x7fff + ((u >> 16) & 1);
    return (u16)(u >> 16);
}

// ---- fp8 e4m3 helpers (HW cvt if available, exact software fallback) ----
__device__ inline floatx2 f8lo(uint v) {
#if __has_builtin(__builtin_amdgcn_cvt_pk_f32_fp8)
    return __builtin_amdgcn_cvt_pk_f32_fp8((int)v, false);
#else
    uint b0 = v & 0xffu, b1 = (v >> 8) & 0xffu;
    floatx2 r;
    r.x = __uint_as_float(((b0 & 0x80u) << 24) | ((b0 & 0x7fu) << 20)) * 0x1p120f;
    r.y = __uint_as_float(((b1 & 0x80u) << 24) | ((b1 & 0x7fu) << 20)) * 0x1p120f;
    return r;
#endif
}
__device__ inline floatx2 f8hi(uint v) {
#if __has_builtin(__builtin_amdgcn_cvt_pk_f32_fp8)
    return __builtin_amdgcn_cvt_pk_f32_fp8((int)v, true);
#else
    uint b0 = (v >> 16) & 0xffu, b1 = (v >> 24) & 0xffu;
    floatx2 r;
    r.x = __uint_as_float(((b0 & 0x80u) << 24) | ((b0 & 0x7fu) << 20)) * 0x1p120f;
    r.y = __uint_as_float(((b1 & 0x80u) << 24) | ((b1 & 0x7fu) << 20)) * 0x1p120f;
    return r;
#endif
}
__device__ inline uint enc8(float f) {
    uint ub = __float_as_uint(f * 0x1p-120f);
    uint s = (ub >> 24) & 0x80u;
    uint mag = ub & 0x7fffffffu;
    mag += 0x7ffffu + ((mag >> 20) & 1u);
    uint r = mag >> 20;
    if (r > 0x7eu) r = 0x7eu;
    return r | s;
}
__device__ inline uint packf8x4(float a, float b, float c, float d) {
#if __has_builtin(__builtin_amdgcn_cvt_pk_fp8_f32)
    int p = __builtin_amdgcn_cvt_pk_fp8_f32(a, b, 0, false);
    p = __builtin_amdgcn_cvt_pk_fp8_f32(c, d, p, true);
    return (uint)p;
#else
    return enc8(a) | (enc8(b) << 8) | (enc8(c) << 16) | (enc8(d) << 24);
#endif
}

// ---------------- pack W (blocks 0..191) + mask detect (blocks 192..255) ----------------
__global__ __launch_bounds__(256) void pack_detect_kernel(
    const float* __restrict__ W1l, const float* __restrict__ W1r,
    const float* __restrict__ W2l, const float* __restrict__ W2r,
    u16* __restrict__ Wp1, u16* __restrict__ Wp2,
    const int* __restrict__ tm, int n_int, int* __restrict__ gflags) {
    if (blockIdx.x < 192) {
        int id = blockIdx.x * 256 + threadIdx.x;
        if (id < 32768) {
            int frag = id >> 9, e = id & 511;
            int lane = e >> 3, j = e & 7;
            int kc = frag >> 4, tn = frag & 15;
            int k = kc * 32 + (lane >> 4) * 8 + j;
            int ncol = tn * 16 + (lane & 15);
            float v = (ncol < 128) ? W1l[k * 128 + ncol] : W1r[k * 128 + ncol - 128];
            Wp1[id] = pb(v);
        } else if (id < 49152) {
            int id2 = id - 32768;
            int frag = id2 >> 9, e = id2 & 511;
            int lane = e >> 3, j = e & 7;
            int kc = frag >> 3, tn = frag & 7;
            int k = kc * 32 + (lane >> 4) * 8 + j;
            int ncol = tn * 16 + (lane & 15);
            float v = (ncol < 64) ? W2l[k * 64 + ncol] : W2r[k * 64 + ncol - 64];
            Wp2[id2] = pb(v);
        }
    } else {
        int i = (blockIdx.x - 192) * 256 + threadIdx.x;
        bool hf = false, ho = false;
        for (; i < n_int; i += 64 * 256) {
            int v = tm[i];
            hf |= (v == 0x3F800000);
            ho |= (v != 0 && v != 1 && v != 0x3F800000);
        }
        if (__any(hf) && (threadIdx.x & 63) == 0) atomicOr(&gflags[0], 1);
        if (__any(ho) && (threadIdx.x & 63) == 0) atomicOr(&gflags[1], 1);
    }
}

// ---------------- CSR build ----------------
__global__ __launch_bounds__(256) void hist_kernel(const int* __restrict__ dst, int e,
                                                   int* __restrict__ counts) {
    int base = (blockIdx.x * 256 + threadIdx.x) * 4;
    if (base + 4 <= e) {
        intx4 d = __builtin_nontemporal_load((const intx4*)(dst + base));
        atomicAdd(&counts[d.x], 1);
        atomicAdd(&counts[d.y], 1);
        atomicAdd(&counts[d.z], 1);
        atomicAdd(&counts[d.w], 1);
    } else {
        for (int i = base; i < e; ++i) atomicAdd(&counts[dst[i]], 1);
    }
}

__global__ __launch_bounds__(256) void scan_partial_kernel(const int* __restrict__ counts, int n,
                                                           int* __restrict__ partials) {
    int t = threadIdx.x;
    int base = blockIdx.x * 1024 + t * 4;
    int s = 0;
    if (base + 3 < n) {
        int4 v = *(const int4*)&counts[base];
        s = v.x + v.y + v.z + v.w;
    } else {
        for (int i = 0; i < 4; ++i) if (base + i < n) s += counts[base + i];
    }
    #pragma unroll
    for (int d = 32; d; d >>= 1) s += __shfl_down(s, d, 64);
    __shared__ int wsum[4];
    if ((t & 63) == 0) wsum[t >> 6] = s;
    __syncthreads();
    if (t == 0) partials[blockIdx.x] = wsum[0] + wsum[1] + wsum[2] + wsum[3];
}

__global__ void scan_top_kernel(int* __restrict__ partials, int nparts, int* __restrict__ total_out) {
    int lane = threadIdx.x;
    int v = (lane < nparts) ? partials[lane] : 0;
    int incl = v;
    #pragma unroll
    for (int d = 1; d < 64; d <<= 1) {
        int u = __shfl_up(incl, d, 64);
        if (lane >= d) incl += u;
    }
    if (lane < nparts) partials[lane] = incl - v;
    if (lane == 63) *total_out = incl;
}

__global__ __launch_bounds__(256) void scan_final_kernel(const int* __restrict__ counts, int n,
                                                         const int* __restrict__ partials,
                                                         int* __restrict__ offsets,
                                                         int* __restrict__ cursor) {
    int t = threadIdx.x;
    int base = blockIdx.x * 1024 + t * 4;
    int v0 = 0, v1 = 0, v2 = 0, v3 = 0;
    if (base + 3 < n) {
        int4 q = *(const int4*)&counts[base];
        v0 = q.x; v1 = q.y; v2 = q.z; v3 = q.w;
    } else {
        if (base + 0 < n) v0 = counts[base + 0];
        if (base + 1 < n) v1 = counts[base + 1];
        if (base + 2 < n) v2 = counts[base + 2];
        if (base + 3 < n) v3 = counts[base + 3];
    }
    int s = v0 + v1 + v2 + v3;
    int lane = t & 63, wid = t >> 6;
    int incl = s;
    #pragma unroll
    for (int d = 1; d < 64; d <<= 1) {
        int u = __shfl_up(incl, d, 64);
        if (lane >= d) incl += u;
    }
    __shared__ int wsum[4];
    if (lane == 63) wsum[wid] = incl;
    __syncthreads();
    int woff = 0;
    #pragma unroll
    for (int i = 0; i < 4; ++i) if (i < wid) woff += wsum[i];
    int run = partials[blockIdx.x] + woff + incl - s;
    if (base + 0 < n) { offsets[base + 0] = run; cursor[base + 0] = run; run += v0; }
    if (base + 1 < n) { offsets[base + 1] = run; cursor[base + 1] = run; run += v1; }
    if (base + 2 < n) { offsets[base + 2] = run; cursor[base + 2] = run; run += v2; }
    if (base + 3 < n) { offsets[base + 3] = run; cursor[base + 3] = run; run += v3; }
}

template <typename IT>
__global__ __launch_bounds__(256) void scatter_kernel(const int* __restrict__ src,
                                                      const int* __restrict__ dst, int e,
                                                      int* __restrict__ cursor,
                                                      IT* __restrict__ csr_src) {
    int base = (blockIdx.x * 256 + threadIdx.x) * 4;
    if (base + 4 <= e) {
        intx4 s = __builtin_nontemporal_load((const intx4*)(src + base));
        intx4 d = __builtin_nontemporal_load((const intx4*)(dst + base));
        int p0 = atomicAdd(&cursor[d.x], 1);
        int p1 = atomicAdd(&cursor[d.y], 1);
        int p2 = atomicAdd(&cursor[d.z], 1);
        int p3 = atomicAdd(&cursor[d.w], 1);
        __builtin_nontemporal_store((IT)s.x, csr_src + p0);
        __builtin_nontemporal_store((IT)s.y, csr_src + p1);
        __builtin_nontemporal_store((IT)s.z, csr_src + p2);
        __builtin_nontemporal_store((IT)s.w, csr_src + p3);
    } else {
        for (int i = base; i < e; ++i) {
            int p = atomicAdd(&cursor[dst[i]], 1);
            csr_src[p] = (IT)src[i];
        }
    }
}

// ---------------- gemm1 (MFMA): P1 = fp8(x@W1l), Q1 = bf16(x@W1r + b1) ----------------
__global__ __launch_bounds__(256) void gemm1_mfma(
    const float* __restrict__ X, const u16* __restrict__ Wp1,
    const float* __restrict__ b1,
    uint* __restrict__ P1f8, uint* __restrict__ Q1u, int n) {
    __shared__ u16 ep[4][16][260];
    int t = threadIdx.x;
    int w = t >> 6, lane = t & 63;
    int q = lane >> 4, c = lane & 15;
    int m0 = blockIdx.x * 64 + w * 16;
    int me = min(m0 + c, n - 1);
    const float* xrow = X + (size_t)me * 128 + q * 8;
    const u16* wbase = Wp1 + lane * 8;

    floatx4 acc[16];
    #pragma unroll
    for (int i = 0; i < 16; ++i) acc[i] = (floatx4){0.f, 0.f, 0.f, 0.f};

    #pragma unroll
    for (int kc = 0; kc < 4; ++kc) {
        float4 x0 = *(const float4*)(xrow + kc * 32);
        float4 x1 = *(const float4*)(xrow + kc * 32 + 4);
        union { short8 s; uint4 u; } a;
        a.u.x = packbf(x0.x, x0.y); a.u.y = packbf(x0.z, x0.w);
        a.u.z = packbf(x1.x, x1.y); a.u.w = packbf(x1.z, x1.w);
        #pragma unroll
        for (int tn = 0; tn < 16; ++tn) {
            union { short8 s; uint4 u; } b;
            b.u = *(const uint4*)(wbase + (kc * 16 + tn) * 512);
            acc[tn] = __builtin_amdgcn_mfma_f32_16x16x32_bf16(a.s, b.s, acc[tn], 0, 0, 0);
        }
    }

    #pragma unroll
    for (int tn = 0; tn < 16; ++tn) {
        int col = tn * 16 + c;
        float badd = (tn >= 8) ? b1[col - 128] : 0.f;
        #pragma unroll
        for (int i = 0; i < 4; ++i)
            ep[w][q * 4 + i][col] = pb(acc[tn][i] + badd);
    }
    for (int r = 0; r < 16; ++r) {
        int grow = m0 + r;
        if (grow >= n) break;
        uint2 v = *(const uint2*)&ep[w][r][lane * 4];
        if (lane < 32) {
            float2 e0 = bf2x(v.x), e1 = bf2x(v.y);
            P1f8[(size_t)grow * 32 + lane] = packf8x4(e0.x, e0.y, e1.x, e1.y);
        } else {
            *(uint2*)&Q1u[(size_t)grow * 64 + 2 * (lane - 32)] = v;
        }
    }
}

// ---------------- aggr1: h1 = bf16(relu(mean(P1) + Q1)), half-wave per edge ----------------
template <typename IT>
__global__ __launch_bounds__(256) void aggr1_kernel(
    const uint* __restrict__ P1f8, const uint* __restrict__ Q1u,
    const int* __restrict__ offsets, const IT* __restrict__ csr,
    uint* __restrict__ h1u, int n) {
    int node = (int)((blockIdx.x * (size_t)blockDim.x + threadIdx.x) >> 6);
    int lane = threadIdx.x & 63;
    int l = lane & 31, hw = lane >> 5;
    if (node >= n) return;
    int beg = offsets[node], end = offsets[node + 1];
    float a0 = 0.f, a1 = 0.f, a2 = 0.f, a3 = 0.f;
    int i = beg + hw;
    for (; i + 2 < end; i += 4) {
        int s0 = csr[i], s1 = csr[i + 2];
        uint v0 = P1f8[(size_t)s0 * 32 + l];
        uint v1 = P1f8[(size_t)s1 * 32 + l];
        floatx2 u0 = f8lo(v0), w0 = f8hi(v0);
        floatx2 u1 = f8lo(v1), w1 = f8hi(v1);
        a0 += u0.x + u1.x; a1 += u0.y + u1.y;
        a2 += w0.x + w1.x; a3 += w0.y + w1.y;
    }
    for (; i < end; i += 2) {
        int s = csr[i];
        uint v = P1f8[(size_t)s * 32 + l];
        floatx2 u = f8lo(v), w2 = f8hi(v);
        a0 += u.x; a1 += u.y; a2 += w2.x; a3 += w2.y;
    }
    a0 += __shfl_xor(a0, 32, 64);
    a1 += __shfl_xor(a1, 32, 64);
    a2 += __shfl_xor(a2, 32, 64);
    a3 += __shfl_xor(a3, 32, 64);
    if (hw == 0) {
        float inv = 1.0f / (float)max(end - beg, 1);
        uint2 qv = *(const uint2*)&Q1u[(size_t)node * 64 + l * 2];
        float2 q0 = bf2x(qv.x), q1 = bf2x(qv.y);
        float r0 = fmaxf(fmaf(a0, inv, q0.x), 0.f);
        float r1 = fmaxf(fmaf(a1, inv, q0.y), 0.f);
        float r2 = fmaxf(fmaf(a2, inv, q1.x), 0.f);
        float r3 = fmaxf(fmaf(a3, inv, q1.y), 0.f);
        uint2 o;
        o.x = packbf(r0, r1);
        o.y = packbf(r2, r3);
        *(uint2*)&h1u[(size_t)node * 64 + l * 2] = o;
    }
}

// ---------------- gemm2 (MFMA): P2 = fp8(h1@W2l), Q2 = bf16(h1@W2r + b2) ----------------
__global__ __launch_bounds__(256) void gemm2_mfma(
    const uint* __restrict__ H1u, const u16* __restrict__ Wp2,
    const float* __restrict__ b2,
    uint* __restrict__ P2f8, uint* __restrict__ Q2u, int n) {
    __shared__ u16 ep[4][16][132];
    int t = threadIdx.x;
    int w = t >> 6, lane = t & 63;
    int q = lane >> 4, c = lane & 15;
    int m0 = blockIdx.x * 64 + w * 16;
    int me = min(m0 + c, n - 1);
    const u16* hrow = (const u16*)H1u + (size_t)me * 128 + q * 8;
    const u16* wbase = Wp2 + lane * 8;

    floatx4 acc[8];
    #pragma unroll
    for (int i = 0; i < 8; ++i) acc[i] = (floatx4){0.f, 0.f, 0.f, 0.f};

    #pragma unroll
    for (int kc = 0; kc < 4; ++kc) {
        union { short8 s; uint4 u; } a;
        a.u = *(const uint4*)(hrow + kc * 32);
        #pragma unroll
        for (int tn = 0; tn < 8; ++tn) {
            union { short8 s; uint4 u; } b;
            b.u = *(const uint4*)(wbase + (kc * 8 + tn) * 512);
            acc[tn] = __builtin_amdgcn_mfma_f32_16x16x32_bf16(a.s, b.s, acc[tn], 0, 0, 0);
        }
    }

    #pragma unroll
    for (int tn = 0; tn < 8; ++tn) {
        int col = tn * 16 + c;
        float badd = (tn >= 4) ? b2[col - 64] : 0.f;
        #pragma unroll
        for (int i = 0; i < 4; ++i)
            ep[w][q * 4 + i][col] = pb(acc[tn][i] + badd);
    }
    for (int r = 0; r < 16; ++r) {
        int grow = m0 + r;
        if (grow >= n) break;
        if (lane < 16) {
            uint2 v = *(const uint2*)&ep[w][r][lane * 4];
            float2 e0 = bf2x(v.x), e1 = bf2x(v.y);
            P2f8[(size_t)grow * 16 + lane] = packf8x4(e0.x, e0.y, e1.x, e1.y);
        } else if (lane < 48) {
            uint v = *(const uint*)&ep[w][r][64 + (lane - 16) * 2];
            Q2u[(size_t)grow * 32 + (lane - 16)] = v;
        }
    }
}

// ---------------- loss: logits = mean(P2) + Q2 ; log_softmax ; masked NLL ----------------
// 1024 threads = 16 waves = 16 nodes/block. Quarter-wave per edge (4 edges in flight).
template <typename IT>
__global__ __launch_bounds__(1024) void loss_kernel(
    const uint* __restrict__ P2f8, const uint* __restrict__ Q2u,
    const int* __restrict__ offsets, const IT* __restrict__ csr,
    const int* __restrict__ y, const void* __restrict__ tmask,
    const int* __restrict__ gflags, float2* __restrict__ bpart, int n) {
    int wid = threadIdx.x >> 6;
    int node = blockIdx.x * 16 + wid;
    int lane = threadIdx.x & 63;
    int l = lane & 15, qw = lane >> 4;
    float num = 0.f, den = 0.f;
    if (node < n) {
        int beg = offsets[node], end = offsets[node + 1];
        float a0 = 0.f, a1 = 0.f, a2 = 0.f, a3 = 0.f;
        int i = beg + qw;
        for (; i + 4 < end; i += 8) {
            int s0 = csr[i], s1 = csr[i + 4];
            uint v0 = P2f8[(size_t)s0 * 16 + l];
            uint v1 = P2f8[(size_t)s1 * 16 + l];
            floatx2 u0 = f8lo(v0), w0 = f8hi(v0);
            floatx2 u1 = f8lo(v1), w1 = f8hi(v1);
            a0 += u0.x + u1.x; a1 += u0.y + u1.y;
            a2 += w0.x + w1.x; a3 += w0.y + w1.y;
        }
        for (; i < end; i += 4) {
            int s = csr[i];
            uint v = P2f8[(size_t)s * 16 + l];
            floatx2 u = f8lo(v), w2 = f8hi(v);
            a0 += u.x; a1 += u.y; a2 += w2.x; a3 += w2.y;
        }
        #pragma unroll
        for (int d = 16; d <= 32; d <<= 1) {
            a0 += __shfl_xor(a0, d, 64);
            a1 += __shfl_xor(a1, d, 64);
            a2 += __shfl_xor(a2, d, 64);
            a3 += __shfl_xor(a3, d, 64);
        }
        float inv = 1.0f / (float)max(end - beg, 1);
        uint2 qv = *(const uint2*)&Q2u[(size_t)node * 32 + l * 2];
        float2 q0 = bf2x(qv.x), q1 = bf2x(qv.y);
        float L0 = fmaf(a0, inv, q0.x);
        float L1 = fmaf(a1, inv, q0.y);
        float L2 = fmaf(a2, inv, q1.x);
        float L3 = fmaf(a3, inv, q1.y);
        float mx = fmaxf(fmaxf(L0, L1), fmaxf(L2, L3));
        #pragma unroll
        for (int d = 1; d <= 8; d <<= 1) mx = fmaxf(mx, __shfl_xor(mx, d, 64));
        float s = __expf(L0 - mx) + __expf(L1 - mx) + __expf(L2 - mx) + __expf(L3 - mx);
        #pragma unroll
        for (int d = 1; d <= 8; d <<= 1) s += __shfl_xor(s, d, 64);
        int cls = y[node];
        int srcl = (cls >> 2) & 15;
        float c0 = __shfl(L0, srcl, 64);
        float c1 = __shfl(L1, srcl, 64);
        float c2 = __shfl(L2, srcl, 64);
        float c3 = __shfl(L3, srcl, 64);
        int sel = cls & 3;
        float Lc = (sel == 0) ? c0 : (sel == 1) ? c1 : (sel == 2) ? c2 : c3;
        float logp = (Lc - mx) - __logf(s);
        int f = gflags[0] ? 2 : (gflags[1] ? 0 : 1);
        bool m;
        if (f == 0)      m = ((const unsigned char*)tmask)[node] != 0;
        else if (f == 1) m = ((const int*)tmask)[node] != 0;
        else             m = ((const float*)tmask)[node] != 0.f;
        if (m) { num = -logp; den = 1.f; }
    }
    __shared__ float2 wacc[16];
    if (lane == 0) wacc[wid] = make_float2(num, den);
    __syncthreads();
    if (threadIdx.x == 0) {
        float rx = 0.f, ry = 0.f;
        #pragma unroll
        for (int i = 0; i < 16; ++i) { rx += wacc[i].x; ry += wacc[i].y; }
        bpart[blockIdx.x] = make_float2(rx, ry);
    }
}

__global__ __launch_bounds__(1024) void finalize_kernel(const float2* __restrict__ bpart, int nb,
                                                        float* __restrict__ out) {
    int t = threadIdx.x;
    float sx = 0.f, sy = 0.f;
    for (int i = t; i < nb; i += 1024) { float2 v = bpart[i]; sx += v.x; sy += v.y; }
    #pragma unroll
    for (int d = 32; d; d >>= 1) { sx += __shfl_down(sx, d, 64); sy += __shfl_down(sy, d, 64); }
    __shared__ float2 wacc[16];
    if ((t & 63) == 0) wacc[t >> 6] = make_float2(sx, sy);
    __syncthreads();
    if (t == 0) {
        float nx = 0.f, ny = 0.f;
        #pragma unroll
        for (int i = 0; i < 16; ++i) { nx += wacc[i].x; ny += wacc[i].y; }
        out[0] = nx / fmaxf(ny, 1.f);
    }
}

extern "C" void kernel_launch(void* const* d_in, const int* in_sizes, int n_in,
                              void* d_out, int out_size, void* d_ws, size_t ws_size,
                              hipStream_t stream) {
    const float* x        = (const float*)d_in[0];
    const int*   edge_src = (const int*)d_in[1];
    const int*   edge_dst = (const int*)d_in[2];
    const int*   y        = (const int*)d_in[3];
    const void*  tmask    = (const void*)d_in[4];
    const float* W1l      = (const float*)d_in[5];
    const float* b1       = (const float*)d_in[6];
    const float* W1r      = (const float*)d_in[7];
    const float* W2l      = (const float*)d_in[8];
    const float* b2       = (const float*)d_in[9];
    const float* W2r      = (const float*)d_in[10];

    const int N = in_sizes[0] / DIN;
    const int E = in_sizes[1];
    const int nb_loss = (N + 15) / 16;
    const bool small_idx = (N <= 65535);

    char* ws = (char*)d_ws;
    int* gflags = (int*)ws;  // 2 ints
    size_t off = 256;
    int* counts   = (int*)(ws + off); off += al256((size_t)N * 4);
    int* offsets  = (int*)(ws + off); off += al256(((size_t)N + 1) * 4);
    int* cursor   = (int*)(ws + off); off += al256((size_t)N * 4);
    void* csr     = (void*)(ws + off); off += al256((size_t)E * 4);  // u16 uses half
    int* spart    = (int*)(ws + off); off += al256(64 * 4);
    float2* bpart = (float2*)(ws + off); off += al256((size_t)nb_loss * 8);
    u16* Wp1      = (u16*)(ws + off); off += al256(32768 * 2);
    u16* Wp2      = (u16*)(ws + off); off += al256(16384 * 2);
    uint* P1f8    = (uint*)(ws + off); off += al256((size_t)N * 32 * 4);   // 6.4 MB (fp8 x 128)
    uint* h1u     = (uint*)(ws + off); off += al256((size_t)N * 64 * 4);   // 12.8 MB (bf16 x 128)
    uint* Q1u     = (uint*)(ws + off); off += al256((size_t)N * 64 * 4);   // 12.8 MB (bf16 x 128)
    // P2/Q2 overlay the dead Q1 region (Q1 last read by aggr1, before gemm2)
    uint* P2f8    = Q1u;                      // N*16 uints (fp8 x 64)
    uint* Q2u     = Q1u + (size_t)N * 16;     // N*32 uints (bf16 x 64)

    hipMemsetAsync(ws, 0, 256, stream);
    hipMemsetAsync(counts, 0, (size_t)N * 4, stream);

    pack_detect_kernel<<<256, 256, 0, stream>>>(W1l, W1r, W2l, W2r, Wp1, Wp2,
                                                (const int*)tmask, N / 4, gflags);

    int eb4 = (E + 1023) / 1024;  // 4 edges per thread
    hist_kernel<<<eb4, 256, 0, stream>>>(edge_dst, E, counts);

    int sb = (N + 1023) / 1024;
    scan_partial_kernel<<<sb, 256, 0, stream>>>(counts, N, spart);
    scan_top_kernel<<<1, 64, 0, stream>>>(spart, sb, &offsets[N]);
    scan_final_kernel<<<sb, 256, 0, stream>>>(counts, N, spart, offsets, cursor);

    if (small_idx)
        scatter_kernel<u16><<<eb4, 256, 0, stream>>>(edge_src, edge_dst, E, cursor, (u16*)csr);
    else
        scatter_kernel<uint><<<eb4, 256, 0, stream>>>(edge_src, edge_dst, E, cursor, (uint*)csr);

    int gb = (N + 63) / 64;
    int ab = (N + 3) / 4;

    // layer 1: transform-then-aggregate (mean_aggr(x)@W = mean_aggr(x@W))
    gemm1_mfma<<<gb, 256, 0, stream>>>(x, Wp1, b1, P1f8, Q1u, N);
    if (small_idx)
        aggr1_kernel<u16><<<ab, 256, 0, stream>>>(P1f8, Q1u, offsets, (const u16*)csr, h1u, N);
    else
        aggr1_kernel<uint><<<ab, 256, 0, stream>>>(P1f8, Q1u, offsets, (const uint*)csr, h1u, N);
    // layer 2
    gemm2_mfma<<<gb, 256, 0, stream>>>(h1u, Wp2, b2, P2f8, Q2u, N);
    if (small_idx)
        loss_kernel<u16><<<nb_loss, 1024, 0, stream>>>(P2f8, Q2u, offsets, (const u16*)csr, y, tmask, gflags, bpart, N);
    else
        loss_kernel<uint><<<nb_loss, 1024, 0, stream>>>(P2f8, Q2u, offsets, (const uint*)csr, y, tmask, gflags, bpart, N);

    finalize_kernel<<<1, 1024, 0, stream>>>(bpart, nb_loss, (float*)d_out);
}

// Round 8
// 237.994 us; speedup vs baseline: 2.3780x; 1.1818x over previous
//
#include <hip/hip_runtime.h>
#include <hip/hip_bf16.h>

typedef unsigned int uint;
typedef unsigned short u16;

// Dims fixed by the problem
#define DIN 128
#define DHID 128
#define DOUT 64
#define BSH 8          // bucket = dst >> 8 (256 nodes per bucket)
#define P3CHUNK 8192   // edges per partition block
#define P4MAX 6144     // LDS staging cap per bucket in emit

static inline size_t al256(size_t x) { return (x + 255) & ~(size_t)255; }

typedef __attribute__((ext_vector_type(8))) short short8;
typedef __attribute__((ext_vector_type(4))) float floatx4;
typedef __attribute__((ext_vector_type(2))) float floatx2;
typedef __attribute__((ext_vector_type(4))) int intx4;   // clang vector for nontemporal builtins

// bf16 pair helpers (uint = two bf16, low bits = even feature)
__device__ inline float2 bf2x(uint v) {
    return make_float2(__uint_as_float(v << 16), __uint_as_float(v & 0xffff0000u));
}
__device__ inline uint packbf(float a, float b) {
    uint ua = __float_as_uint(a), ub = __float_as_uint(b);
    ua += 0x7fff + ((ua >> 16) & 1);   // RNE
    ub += 0x7fff + ((ub >> 16) & 1);
    return (ua >> 16) | (ub & 0xffff0000u);
}
__device__ inline u16 pb(float a) {
    uint u = __float_as_uint(a);
    u += 0x7fff + ((u >> 16) & 1);
    return (u16)(u >> 16);
}

// ---- fp8 e4m3 helpers (HW cvt if available, exact software fallback) ----
__device__ inline floatx2 f8lo(uint v) {
#if __has_builtin(__builtin_amdgcn_cvt_pk_f32_fp8)
    return __builtin_amdgcn_cvt_pk_f32_fp8((int)v, false);
#else
    uint b0 = v & 0xffu, b1 = (v >> 8) & 0xffu;
    floatx2 r;
    r.x = __uint_as_float(((b0 & 0x80u) << 24) | ((b0 & 0x7fu) << 20)) * 0x1p120f;
    r.y = __uint_as_float(((b1 & 0x80u) << 24) | ((b1 & 0x7fu) << 20)) * 0x1p120f;
    return r;
#endif
}
__device__ inline floatx2 f8hi(uint v) {
#if __has_builtin(__builtin_amdgcn_cvt_pk_f32_fp8)
    return __builtin_amdgcn_cvt_pk_f32_fp8((int)v, true);
#else
    uint b0 = (v >> 16) & 0xffu, b1 = (v >> 24) & 0xffu;
    floatx2 r;
    r.x = __uint_as_float(((b0 & 0x80u) << 24) | ((b0 & 0x7fu) << 20)) * 0x1p120f;
    r.y = __uint_as_float(((b1 & 0x80u) << 24) | ((b1 & 0x7fu) << 20)) * 0x1p120f;
    return r;
#endif
}
__device__ inline uint enc8(float f) {
    uint ub = __float_as_uint(f * 0x1p-120f);
    uint s = (ub >> 24) & 0x80u;
    uint mag = ub & 0x7fffffffu;
    mag += 0x7ffffu + ((mag >> 20) & 1u);
    uint r = mag >> 20;
    if (r > 0x7eu) r = 0x7eu;
    return r | s;
}
__device__ inline uint packf8x4(float a, float b, float c, float d) {
#if __has_builtin(__builtin_amdgcn_cvt_pk_fp8_f32)
    int p = __builtin_amdgcn_cvt_pk_fp8_f32(a, b, 0, false);
    p = __builtin_amdgcn_cvt_pk_fp8_f32(c, d, p, true);
    return (uint)p;
#else
    return enc8(a) | (enc8(b) << 8) | (enc8(c) << 16) | (enc8(d) << 24);
#endif
}

// ---------------- pack W (blocks 0..191) + mask detect (blocks 192..255) ----------------
__global__ __launch_bounds__(256) void pack_detect_kernel(
    const float* __restrict__ W1l, const float* __restrict__ W1r,
    const float* __restrict__ W2l, const float* __restrict__ W2r,
    u16* __restrict__ Wp1, u16* __restrict__ Wp2,
    const int* __restrict__ tm, int n_int, int* __restrict__ gflags) {
    if (blockIdx.x < 192) {
        int id = blockIdx.x * 256 + threadIdx.x;
        if (id < 32768) {
            int frag = id >> 9, e = id & 511;
            int lane = e >> 3, j = e & 7;
            int kc = frag >> 4, tn = frag & 15;
            int k = kc * 32 + (lane >> 4) * 8 + j;
            int ncol = tn * 16 + (lane & 15);
            float v = (ncol < 128) ? W1l[k * 128 + ncol] : W1r[k * 128 + ncol - 128];
            Wp1[id] = pb(v);
        } else if (id < 49152) {
            int id2 = id - 32768;
            int frag = id2 >> 9, e = id2 & 511;
            int lane = e >> 3, j = e & 7;
            int kc = frag >> 3, tn = frag & 7;
            int k = kc * 32 + (lane >> 4) * 8 + j;
            int ncol = tn * 16 + (lane & 15);
            float v = (ncol < 64) ? W2l[k * 64 + ncol] : W2r[k * 64 + ncol - 64];
            Wp2[id2] = pb(v);
        }
    } else {
        int i = (blockIdx.x - 192) * 256 + threadIdx.x;
        bool hf = false, ho = false;
        for (; i < n_int; i += 64 * 256) {
            int v = tm[i];
            hf |= (v == 0x3F800000);
            ho |= (v != 0 && v != 1 && v != 0x3F800000);
        }
        if (__any(hf) && (threadIdx.x & 63) == 0) atomicOr(&gflags[0], 1);
        if (__any(ho) && (threadIdx.x & 63) == 0) atomicOr(&gflags[1], 1);
    }
}

// ================= CSR build: two-level counting sort (N <= 65535) =================
// Pass 1: bucket histogram (bucket = dst >> BSH), LDS-aggregated
__global__ __launch_bounds__(256) void bhist_kernel(const int* __restrict__ dst, int e, int nb,
                                                    uint* __restrict__ bcounts) {
    __shared__ uint lh[512];
    for (int i = threadIdx.x; i < 512; i += 256) lh[i] = 0;
    __syncthreads();
    int nquad = (e + 3) >> 2;
    for (int i = blockIdx.x * 256 + threadIdx.x; i < nquad; i += gridDim.x * 256) {
        int base = i * 4;
        if (base + 4 <= e) {
            intx4 d = __builtin_nontemporal_load((const intx4*)(dst + base));
            atomicAdd(&lh[d.x >> BSH], 1u);
            atomicAdd(&lh[d.y >> BSH], 1u);
            atomicAdd(&lh[d.z >> BSH], 1u);
            atomicAdd(&lh[d.w >> BSH], 1u);
        } else {
            for (int k = base; k < e; ++k) atomicAdd(&lh[dst[k] >> BSH], 1u);
        }
    }
    __syncthreads();
    for (int i = threadIdx.x; i < nb; i += 256) {
        uint c = lh[i];
        if (c) atomicAdd(&bcounts[i], c);
    }
}

// Pass 2: exclusive scan of bucket counts (nb <= 512), init cursors, offsets[n]=e
__global__ __launch_bounds__(256) void bscan_kernel(const uint* __restrict__ bcounts, int nb, int e,
                                                    uint* __restrict__ bbase, uint* __restrict__ bcursor,
                                                    int* __restrict__ offsets, int n) {
    __shared__ uint pws[4];
    int t = threadIdx.x;
    uint v0 = (2 * t < nb) ? bcounts[2 * t] : 0u;
    uint v1 = (2 * t + 1 < nb) ? bcounts[2 * t + 1] : 0u;
    uint s = v0 + v1;
    int lane = t & 63, wv = t >> 6;
    uint incl = s;
    #pragma unroll
    for (int d = 1; d < 64; d <<= 1) {
        uint u = (uint)__shfl_up((int)incl, d, 64);
        if (lane >= d) incl += u;
    }
    if (lane == 63) pws[wv] = incl;
    __syncthreads();
    uint woff = 0;
    #pragma unroll
    for (int i = 0; i < 4; ++i) if (i < wv) woff += pws[i];
    uint excl = woff + incl - s;
    if (2 * t < nb) { bbase[2 * t] = excl; bcursor[2 * t] = excl; }
    if (2 * t + 1 < nb) { bbase[2 * t + 1] = excl + v0; bcursor[2 * t + 1] = excl + v0; }
    if (t == 0) {
        uint tot = pws[0] + pws[1] + pws[2] + pws[3];
        bbase[nb] = tot;
        offsets[n] = e;
    }
}

// Pass 3: partition edges into bucket-grouped pair array; all global writes coalesced
__global__ __launch_bounds__(256) void partition_kernel(const int* __restrict__ src,
                                                        const int* __restrict__ dst, int e, int nb,
                                                        uint* __restrict__ bcursor,
                                                        uint* __restrict__ pairs) {
    __shared__ uint lh[512], lexcl[512], lbase[512], lpos[512];
    __shared__ uint st[P3CHUNK];
    __shared__ uint pws[4];
    int t = threadIdx.x;
    int e0 = blockIdx.x * P3CHUNK;
    int ecnt = min(P3CHUNK, e - e0);
    for (int i = t; i < 512; i += 256) { lh[i] = 0; lpos[i] = 0; }
    __syncthreads();
    // Phase A: local bucket histogram
    for (int i = t; i < ecnt; i += 256)
        atomicAdd(&lh[dst[e0 + i] >> BSH], 1u);
    __syncthreads();
    // Phase B: local exclusive scan (2 values/thread)
    {
        uint v0 = lh[2 * t], v1 = lh[2 * t + 1];
        uint s = v0 + v1;
        int lane = t & 63, wv = t >> 6;
        uint incl = s;
        #pragma unroll
        for (int d = 1; d < 64; d <<= 1) {
            uint u = (uint)__shfl_up((int)incl, d, 64);
            if (lane >= d) incl += u;
        }
        if (lane == 63) pws[wv] = incl;
        __syncthreads();
        uint woff = 0;
        #pragma unroll
        for (int i = 0; i < 4; ++i) if (i < wv) woff += pws[i];
        uint excl = woff + incl - s;
        lexcl[2 * t] = excl;
        lexcl[2 * t + 1] = excl + v0;
    }
    // claim global space per bucket (one atomic per non-empty bucket)
    __syncthreads();
    for (int b = t; b < nb; b += 256) {
        uint c = lh[b];
        lbase[b] = c ? atomicAdd(&bcursor[b], c) : 0u;
    }
    __syncthreads();
    // Phase C: scatter pairs into LDS grouped by bucket
    for (int i = t; i < ecnt; i += 256) {
        int d = dst[e0 + i];
        int s = src[e0 + i];
        int b = d >> BSH;
        uint slot = lexcl[b] + atomicAdd(&lpos[b], 1u);
        st[slot] = ((uint)(d & ((1 << BSH) - 1)) << 16) | (uint)s;
    }
    __syncthreads();
    // Phase D: coalesced copy of each bucket run to global
    int wv = t >> 6, lane = t & 63;
    for (int b = wv; b < nb; b += 4) {
        uint c = lh[b];
        uint lsrc = lexcl[b], gdst = lbase[b];
        for (uint k = lane; k < c; k += 64)
            pairs[gdst + k] = st[lsrc + k];
    }
}

// Pass 4: per-bucket local sort -> dense csr segment + offsets
__global__ __launch_bounds__(256) void emit_kernel(const uint* __restrict__ pairs,
                                                   const uint* __restrict__ bbase, int n,
                                                   u16* __restrict__ csr, int* __restrict__ offsets) {
    __shared__ uint cnt[256], lex[256];
    __shared__ u16 ob[P4MAX];
    __shared__ uint pws[4];
    int b = blockIdx.x, t = threadIdx.x;
    uint seg0 = bbase[b];
    int len = (int)(bbase[b + 1] - seg0);
    int n0 = b << BSH;
    cnt[t] = 0;
    __syncthreads();
    for (int i = t; i < len; i += 256)
        atomicAdd(&cnt[pairs[seg0 + i] >> 16], 1u);
    __syncthreads();
    // scan 256 counts (1/thread)
    uint v = cnt[t];
    int lane = t & 63, wv = t >> 6;
    uint incl = v;
    #pragma unroll
    for (int d = 1; d < 64; d <<= 1) {
        uint u = (uint)__shfl_up((int)incl, d, 64);
        if (lane >= d) incl += u;
    }
    if (lane == 63) pws[wv] = incl;
    __syncthreads();
    uint woff = 0;
    #pragma unroll
    for (int i = 0; i < 4; ++i) if (i < wv) woff += pws[i];
    uint excl = woff + incl - v;
    lex[t] = excl;
    if (n0 + t < n) offsets[n0 + t] = (int)(seg0 + excl);
    __syncthreads();
    cnt[t] = 0;
    __syncthreads();
    for (int i = t; i < len; i += 256) {
        uint p = pairs[seg0 + i];
        uint loc = p >> 16;
        uint slot = lex[loc] + atomicAdd(&cnt[loc], 1u);
        if (slot < P4MAX) ob[slot] = (u16)(p & 0xffffu);
        else csr[seg0 + slot] = (u16)(p & 0xffffu);   // overflow fallback (dense graphs)
    }
    __syncthreads();
    int lim = min(len, P4MAX);
    for (int i = t; i < lim; i += 256) csr[seg0 + i] = ob[i];
}

// ================= fallback CSR build for N > 65535 (old path) =================
__global__ __launch_bounds__(256) void hist_kernel(const int* __restrict__ dst, int e,
                                                   int* __restrict__ counts) {
    int base = (blockIdx.x * 256 + threadIdx.x) * 4;
    if (base + 4 <= e) {
        intx4 d = __builtin_nontemporal_load((const intx4*)(dst + base));
        atomicAdd(&counts[d.x], 1);
        atomicAdd(&counts[d.y], 1);
        atomicAdd(&counts[d.z], 1);
        atomicAdd(&counts[d.w], 1);
    } else {
        for (int i = base; i < e; ++i) atomicAdd(&counts[dst[i]], 1);
    }
}

__global__ __launch_bounds__(256) void scan_partial_kernel(const int* __restrict__ counts, int n,
                                                           int* __restrict__ partials) {
    int t = threadIdx.x;
    int base = blockIdx.x * 1024 + t * 4;
    int s = 0;
    if (base + 3 < n) {
        int4 v = *(const int4*)&counts[base];
        s = v.x + v.y + v.z + v.w;
    } else {
        for (int i = 0; i < 4; ++i) if (base + i < n) s += counts[base + i];
    }
    #pragma unroll
    for (int d = 32; d; d >>= 1) s += __shfl_down(s, d, 64);
    __shared__ int wsum[4];
    if ((t & 63) == 0) wsum[t >> 6] = s;
    __syncthreads();
    if (t == 0) partials[blockIdx.x] = wsum[0] + wsum[1] + wsum[2] + wsum[3];
}

__global__ void scan_top_kernel(int* __restrict__ partials, int nparts, int* __restrict__ total_out) {
    int lane = threadIdx.x;
    int v = (lane < nparts) ? partials[lane] : 0;
    int incl = v;
    #pragma unroll
    for (int d = 1; d < 64; d <<= 1) {
        int u = __shfl_up(incl, d, 64);
        if (lane >= d) incl += u;
    }
    if (lane < nparts) partials[lane] = incl - v;
    if (lane == 63) *total_out = incl;
}

__global__ __launch_bounds__(256) void scan_final_kernel(const int* __restrict__ counts, int n,
                                                         const int* __restrict__ partials,
                                                         int* __restrict__ offsets,
                                                         int* __restrict__ cursor) {
    int t = threadIdx.x;
    int base = blockIdx.x * 1024 + t * 4;
    int v0 = 0, v1 = 0, v2 = 0, v3 = 0;
    if (base + 3 < n) {
        int4 q = *(const int4*)&counts[base];
        v0 = q.x; v1 = q.y; v2 = q.z; v3 = q.w;
    } else {
        if (base + 0 < n) v0 = counts[base + 0];
        if (base + 1 < n) v1 = counts[base + 1];
        if (base + 2 < n) v2 = counts[base + 2];
        if (base + 3 < n) v3 = counts[base + 3];
    }
    int s = v0 + v1 + v2 + v3;
    int lane = t & 63, wid = t >> 6;
    int incl = s;
    #pragma unroll
    for (int d = 1; d < 64; d <<= 1) {
        int u = __shfl_up(incl, d, 64);
        if (lane >= d) incl += u;
    }
    __shared__ int wsum[4];
    if (lane == 63) wsum[wid] = incl;
    __syncthreads();
    int woff = 0;
    #pragma unroll
    for (int i = 0; i < 4; ++i) if (i < wid) woff += wsum[i];
    int run = partials[blockIdx.x] + woff + incl - s;
    if (base + 0 < n) { offsets[base + 0] = run; cursor[base + 0] = run; run += v0; }
    if (base + 1 < n) { offsets[base + 1] = run; cursor[base + 1] = run; run += v1; }
    if (base + 2 < n) { offsets[base + 2] = run; cursor[base + 2] = run; run += v2; }
    if (base + 3 < n) { offsets[base + 3] = run; cursor[base + 3] = run; run += v3; }
}

__global__ __launch_bounds__(256) void scatter_kernel(const int* __restrict__ src,
                                                      const int* __restrict__ dst, int e,
                                                      int* __restrict__ cursor,
                                                      uint* __restrict__ csr_src) {
    int base = (blockIdx.x * 256 + threadIdx.x) * 4;
    if (base + 4 <= e) {
        intx4 s = __builtin_nontemporal_load((const intx4*)(src + base));
        intx4 d = __builtin_nontemporal_load((const intx4*)(dst + base));
        int p0 = atomicAdd(&cursor[d.x], 1);
        int p1 = atomicAdd(&cursor[d.y], 1);
        int p2 = atomicAdd(&cursor[d.z], 1);
        int p3 = atomicAdd(&cursor[d.w], 1);
        csr_src[p0] = (uint)s.x;
        csr_src[p1] = (uint)s.y;
        csr_src[p2] = (uint)s.z;
        csr_src[p3] = (uint)s.w;
    } else {
        for (int i = base; i < e; ++i) {
            int p = atomicAdd(&cursor[dst[i]], 1);
            csr_src[p] = (uint)src[i];
        }
    }
}

// ---------------- gemm1 (MFMA): P1 = fp8(x@W1l), Q1 = bf16(x@W1r + b1) ----------------
__global__ __launch_bounds__(256) void gemm1_mfma(
    const float* __restrict__ X, const u16* __restrict__ Wp1,
    const float* __restrict__ b1,
    uint* __restrict__ P1f8, uint* __restrict__ Q1u, int n) {
    __shared__ u16 ep[4][16][260];
    int t = threadIdx.x;
    int w = t >> 6, lane = t & 63;
    int q = lane >> 4, c = lane & 15;
    int m0 = blockIdx.x * 64 + w * 16;
    int me = min(m0 + c, n - 1);
    const float* xrow = X + (size_t)me * 128 + q * 8;
    const u16* wbase = Wp1 + lane * 8;

    floatx4 acc[16];
    #pragma unroll
    for (int i = 0; i < 16; ++i) acc[i] = (floatx4){0.f, 0.f, 0.f, 0.f};

    #pragma unroll
    for (int kc = 0; kc < 4; ++kc) {
        float4 x0 = *(const float4*)(xrow + kc * 32);
        float4 x1 = *(const float4*)(xrow + kc * 32 + 4);
        union { short8 s; uint4 u; } a;
        a.u.x = packbf(x0.x, x0.y); a.u.y = packbf(x0.z, x0.w);
        a.u.z = packbf(x1.x, x1.y); a.u.w = packbf(x1.z, x1.w);
        #pragma unroll
        for (int tn = 0; tn < 16; ++tn) {
            union { short8 s; uint4 u; } b;
            b.u = *(const uint4*)(wbase + (kc * 16 + tn) * 512);
            acc[tn] = __builtin_amdgcn_mfma_f32_16x16x32_bf16(a.s, b.s, acc[tn], 0, 0, 0);
        }
    }

    #pragma unroll
    for (int tn = 0; tn < 16; ++tn) {
        int col = tn * 16 + c;
        float badd = (tn >= 8) ? b1[col - 128] : 0.f;
        #pragma unroll
        for (int i = 0; i < 4; ++i)
            ep[w][q * 4 + i][col] = pb(acc[tn][i] + badd);
    }
    for (int r = 0; r < 16; ++r) {
        int grow = m0 + r;
        if (grow >= n) break;
        uint2 v = *(const uint2*)&ep[w][r][lane * 4];
        if (lane < 32) {
            float2 e0 = bf2x(v.x), e1 = bf2x(v.y);
            P1f8[(size_t)grow * 32 + lane] = packf8x4(e0.x, e0.y, e1.x, e1.y);
        } else {
            *(uint2*)&Q1u[(size_t)grow * 64 + 2 * (lane - 32)] = v;
        }
    }
}

// ---------------- aggr1: h1 = bf16(relu(mean(P1) + Q1)), half-wave per edge ----------------
template <typename IT>
__global__ __launch_bounds__(256) void aggr1_kernel(
    const uint* __restrict__ P1f8, const uint* __restrict__ Q1u,
    const int* __restrict__ offsets, const IT* __restrict__ csr,
    uint* __restrict__ h1u, int n) {
    int node = (int)((blockIdx.x * (size_t)blockDim.x + threadIdx.x) >> 6);
    int lane = threadIdx.x & 63;
    int l = lane & 31, hw = lane >> 5;
    if (node >= n) return;
    int beg = offsets[node], end = offsets[node + 1];
    float a0 = 0.f, a1 = 0.f, a2 = 0.f, a3 = 0.f;
    int i = beg + hw;
    for (; i + 2 < end; i += 4) {
        int s0 = csr[i], s1 = csr[i + 2];
        uint v0 = P1f8[(size_t)s0 * 32 + l];
        uint v1 = P1f8[(size_t)s1 * 32 + l];
        floatx2 u0 = f8lo(v0), w0 = f8hi(v0);
        floatx2 u1 = f8lo(v1), w1 = f8hi(v1);
        a0 += u0.x + u1.x; a1 += u0.y + u1.y;
        a2 += w0.x + w1.x; a3 += w0.y + w1.y;
    }
    for (; i < end; i += 2) {
        int s = csr[i];
        uint v = P1f8[(size_t)s * 32 + l];
        floatx2 u = f8lo(v), w2 = f8hi(v);
        a0 += u.x; a1 += u.y; a2 += w2.x; a3 += w2.y;
    }
    a0 += __shfl_xor(a0, 32, 64);
    a1 += __shfl_xor(a1, 32, 64);
    a2 += __shfl_xor(a2, 32, 64);
    a3 += __shfl_xor(a3, 32, 64);
    if (hw == 0) {
        float inv = 1.0f / (float)max(end - beg, 1);
        uint2 qv = *(const uint2*)&Q1u[(size_t)node * 64 + l * 2];
        float2 q0 = bf2x(qv.x), q1 = bf2x(qv.y);
        float r0 = fmaxf(fmaf(a0, inv, q0.x), 0.f);
        float r1 = fmaxf(fmaf(a1, inv, q0.y), 0.f);
        float r2 = fmaxf(fmaf(a2, inv, q1.x), 0.f);
        float r3 = fmaxf(fmaf(a3, inv, q1.y), 0.f);
        uint2 o;
        o.x = packbf(r0, r1);
        o.y = packbf(r2, r3);
        *(uint2*)&h1u[(size_t)node * 64 + l * 2] = o;
    }
}

// ---------------- gemm2 (MFMA): P2 = fp8(h1@W2l), Q2 = bf16(h1@W2r + b2) ----------------
__global__ __launch_bounds__(256) void gemm2_mfma(
    const uint* __restrict__ H1u, const u16* __restrict__ Wp2,
    const float* __restrict__ b2,
    uint* __restrict__ P2f8, uint* __restrict__ Q2u, int n) {
    __shared__ u16 ep[4][16][132];
    int t = threadIdx.x;
    int w = t >> 6, lane = t & 63;
    int q = lane >> 4, c = lane & 15;
    int m0 = blockIdx.x * 64 + w * 16;
    int me = min(m0 + c, n - 1);
    const u16* hrow = (const u16*)H1u + (size_t)me * 128 + q * 8;
    const u16* wbase = Wp2 + lane * 8;

    floatx4 acc[8];
    #pragma unroll
    for (int i = 0; i < 8; ++i) acc[i] = (floatx4){0.f, 0.f, 0.f, 0.f};

    #pragma unroll
    for (int kc = 0; kc < 4; ++kc) {
        union { short8 s; uint4 u; } a;
        a.u = *(const uint4*)(hrow + kc * 32);
        #pragma unroll
        for (int tn = 0; tn < 8; ++tn) {
            union { short8 s; uint4 u; } b;
            b.u = *(const uint4*)(wbase + (kc * 8 + tn) * 512);
            acc[tn] = __builtin_amdgcn_mfma_f32_16x16x32_bf16(a.s, b.s, acc[tn], 0, 0, 0);
        }
    }

    #pragma unroll
    for (int tn = 0; tn < 8; ++tn) {
        int col = tn * 16 + c;
        float badd = (tn >= 4) ? b2[col - 64] : 0.f;
        #pragma unroll
        for (int i = 0; i < 4; ++i)
            ep[w][q * 4 + i][col] = pb(acc[tn][i] + badd);
    }
    for (int r = 0; r < 16; ++r) {
        int grow = m0 + r;
        if (grow >= n) break;
        if (lane < 16) {
            uint2 v = *(const uint2*)&ep[w][r][lane * 4];
            float2 e0 = bf2x(v.x), e1 = bf2x(v.y);
            P2f8[(size_t)grow * 16 + lane] = packf8x4(e0.x, e0.y, e1.x, e1.y);
        } else if (lane < 48) {
            uint v = *(const uint*)&ep[w][r][64 + (lane - 16) * 2];
            Q2u[(size_t)grow * 32 + (lane - 16)] = v;
        }
    }
}

// ---------------- loss: logits = mean(P2) + Q2 ; log_softmax ; masked NLL ----------------
template <typename IT>
__global__ __launch_bounds__(1024) void loss_kernel(
    const uint* __restrict__ P2f8, const uint* __restrict__ Q2u,
    const int* __restrict__ offsets, const IT* __restrict__ csr,
    const int* __restrict__ y, const void* __restrict__ tmask,
    const int* __restrict__ gflags, float2* __restrict__ bpart, int n) {
    int wid = threadIdx.x >> 6;
    int node = blockIdx.x * 16 + wid;
    int lane = threadIdx.x & 63;
    int l = lane & 15, qw = lane >> 4;
    float num = 0.f, den = 0.f;
    if (node < n) {
        int beg = offsets[node], end = offsets[node + 1];
        float a0 = 0.f, a1 = 0.f, a2 = 0.f, a3 = 0.f;
        int i = beg + qw;
        for (; i + 4 < end; i += 8) {
            int s0 = csr[i], s1 = csr[i + 4];
            uint v0 = P2f8[(size_t)s0 * 16 + l];
            uint v1 = P2f8[(size_t)s1 * 16 + l];
            floatx2 u0 = f8lo(v0), w0 = f8hi(v0);
            floatx2 u1 = f8lo(v1), w1 = f8hi(v1);
            a0 += u0.x + u1.x; a1 += u0.y + u1.y;
            a2 += w0.x + w1.x; a3 += w0.y + w1.y;
        }
        for (; i < end; i += 4) {
            int s = csr[i];
            uint v = P2f8[(size_t)s * 16 + l];
            floatx2 u = f8lo(v), w2 = f8hi(v);
            a0 += u.x; a1 += u.y; a2 += w2.x; a3 += w2.y;
        }
        #pragma unroll
        for (int d = 16; d <= 32; d <<= 1) {
            a0 += __shfl_xor(a0, d, 64);
            a1 += __shfl_xor(a1, d, 64);
            a2 += __shfl_xor(a2, d, 64);
            a3 += __shfl_xor(a3, d, 64);
        }
        float inv = 1.0f / (float)max(end - beg, 1);
        uint2 qv = *(const uint2*)&Q2u[(size_t)node * 32 + l * 2];
        float2 q0 = bf2x(qv.x), q1 = bf2x(qv.y);
        float L0 = fmaf(a0, inv, q0.x);
        float L1 = fmaf(a1, inv, q0.y);
        float L2 = fmaf(a2, inv, q1.x);
        float L3 = fmaf(a3, inv, q1.y);
        float mx = fmaxf(fmaxf(L0, L1), fmaxf(L2, L3));
        #pragma unroll
        for (int d = 1; d <= 8; d <<= 1) mx = fmaxf(mx, __shfl_xor(mx, d, 64));
        float s = __expf(L0 - mx) + __expf(L1 - mx) + __expf(L2 - mx) + __expf(L3 - mx);
        #pragma unroll
        for (int d = 1; d <= 8; d <<= 1) s += __shfl_xor(s, d, 64);
        int cls = y[node];
        int srcl = (cls >> 2) & 15;
        float c0 = __shfl(L0, srcl, 64);
        float c1 = __shfl(L1, srcl, 64);
        float c2 = __shfl(L2, srcl, 64);
        float c3 = __shfl(L3, srcl, 64);
        int sel = cls & 3;
        float Lc = (sel == 0) ? c0 : (sel == 1) ? c1 : (sel == 2) ? c2 : c3;
        float logp = (Lc - mx) - __logf(s);
        int f = gflags[0] ? 2 : (gflags[1] ? 0 : 1);
        bool m;
        if (f == 0)      m = ((const unsigned char*)tmask)[node] != 0;
        else if (f == 1) m = ((const int*)tmask)[node] != 0;
        else             m = ((const float*)tmask)[node] != 0.f;
        if (m) { num = -logp; den = 1.f; }
    }
    __shared__ float2 wacc[16];
    if (lane == 0) wacc[wid] = make_float2(num, den);
    __syncthreads();
    if (threadIdx.x == 0) {
        float rx = 0.f, ry = 0.f;
        #pragma unroll
        for (int i = 0; i < 16; ++i) { rx += wacc[i].x; ry += wacc[i].y; }
        bpart[blockIdx.x] = make_float2(rx, ry);
    }
}

__global__ __launch_bounds__(1024) void finalize_kernel(const float2* __restrict__ bpart, int nb,
                                                        float* __restrict__ out) {
    int t = threadIdx.x;
    float sx = 0.f, sy = 0.f;
    for (int i = t; i < nb; i += 1024) { float2 v = bpart[i]; sx += v.x; sy += v.y; }
    #pragma unroll
    for (int d = 32; d; d >>= 1) { sx += __shfl_down(sx, d, 64); sy += __shfl_down(sy, d, 64); }
    __shared__ float2 wacc[16];
    if ((t & 63) == 0) wacc[t >> 6] = make_float2(sx, sy);
    __syncthreads();
    if (t == 0) {
        float nx = 0.f, ny = 0.f;
        #pragma unroll
        for (int i = 0; i < 16; ++i) { nx += wacc[i].x; ny += wacc[i].y; }
        out[0] = nx / fmaxf(ny, 1.f);
    }
}

extern "C" void kernel_launch(void* const* d_in, const int* in_sizes, int n_in,
                              void* d_out, int out_size, void* d_ws, size_t ws_size,
                              hipStream_t stream) {
    const float* x        = (const float*)d_in[0];
    const int*   edge_src = (const int*)d_in[1];
    const int*   edge_dst = (const int*)d_in[2];
    const int*   y        = (const int*)d_in[3];
    const void*  tmask    = (const void*)d_in[4];
    const float* W1l      = (const float*)d_in[5];
    const float* b1       = (const float*)d_in[6];
    const float* W1r      = (const float*)d_in[7];
    const float* W2l      = (const float*)d_in[8];
    const float* b2       = (const float*)d_in[9];
    const float* W2r      = (const float*)d_in[10];

    const int N = in_sizes[0] / DIN;
    const int E = in_sizes[1];
    const int nb_loss = (N + 15) / 16;
    const bool small_idx = (N <= 65535);
    const int nb = (N + 255) >> BSH;   // buckets (<=512 for small_idx range handled)

    char* ws = (char*)d_ws;
    int* gflags = (int*)ws;  // 2 ints
    size_t off = 256;
    int* offsets  = (int*)(ws + off); off += al256(((size_t)N + 1) * 4);
    uint* bcounts = (uint*)(ws + off); off += al256(513 * 4);
    uint* bbase   = (uint*)(ws + off); off += al256(513 * 4);
    uint* bcursor = (uint*)(ws + off); off += al256(513 * 4);
    uint* pairs   = (uint*)(ws + off); off += al256((size_t)E * 4);
    void* csr     = (void*)(ws + off); off += al256((size_t)E * 4);  // u16 uses half
    int* counts   = (int*)(ws + off); off += al256((size_t)N * 4);   // fallback
    int* cursor   = (int*)(ws + off); off += al256((size_t)N * 4);   // fallback
    int* spart    = (int*)(ws + off); off += al256(64 * 4);          // fallback
    float2* bpart = (float2*)(ws + off); off += al256((size_t)nb_loss * 8);
    u16* Wp1      = (u16*)(ws + off); off += al256(32768 * 2);
    u16* Wp2      = (u16*)(ws + off); off += al256(16384 * 2);
    uint* P1f8    = (uint*)(ws + off); off += al256((size_t)N * 32 * 4);   // 6.4 MB (fp8 x 128)
    uint* h1u     = (uint*)(ws + off); off += al256((size_t)N * 64 * 4);   // 12.8 MB (bf16 x 128)
    uint* Q1u     = (uint*)(ws + off); off += al256((size_t)N * 64 * 4);   // 12.8 MB (bf16 x 128)
    // P2/Q2 overlay the dead Q1 region (Q1 last read by aggr1, before gemm2)
    uint* P2f8    = Q1u;                      // N*16 uints (fp8 x 64)
    uint* Q2u     = Q1u + (size_t)N * 16;     // N*32 uints (bf16 x 64)

    hipMemsetAsync(ws, 0, 256, stream);

    pack_detect_kernel<<<256, 256, 0, stream>>>(W1l, W1r, W2l, W2r, Wp1, Wp2,
                                                (const int*)tmask, N / 4, gflags);

    if (small_idx) {
        hipMemsetAsync(bcounts, 0, 513 * 4, stream);
        bhist_kernel<<<256, 256, 0, stream>>>(edge_dst, E, nb, bcounts);
        bscan_kernel<<<1, 256, 0, stream>>>(bcounts, nb, E, bbase, bcursor, offsets, N);
        int pblocks = (E + P3CHUNK - 1) / P3CHUNK;
        partition_kernel<<<pblocks, 256, 0, stream>>>(edge_src, edge_dst, E, nb, bcursor, pairs);
        emit_kernel<<<nb, 256, 0, stream>>>(pairs, bbase, N, (u16*)csr, offsets);
    } else {
        hipMemsetAsync(counts, 0, (size_t)N * 4, stream);
        int eb4 = (E + 1023) / 1024;
        hist_kernel<<<eb4, 256, 0, stream>>>(edge_dst, E, counts);
        int sb = (N + 1023) / 1024;
        scan_partial_kernel<<<sb, 256, 0, stream>>>(counts, N, spart);
        scan_top_kernel<<<1, 64, 0, stream>>>(spart, sb, &offsets[N]);
        scan_final_kernel<<<sb, 256, 0, stream>>>(counts, N, spart, offsets, cursor);
        scatter_kernel<<<eb4, 256, 0, stream>>>(edge_src, edge_dst, E, cursor, (uint*)csr);
    }

    int gb = (N + 63) / 64;
    int ab = (N + 3) / 4;

    // layer 1: transform-then-aggregate (mean_aggr(x)@W = mean_aggr(x@W))
    gemm1_mfma<<<gb, 256, 0, stream>>>(x, Wp1, b1, P1f8, Q1u, N);
    if (small_idx)
        aggr1_kernel<u16><<<ab, 256, 0, stream>>>(P1f8, Q1u, offsets, (const u16*)csr, h1u, N);
    else
        aggr1_kernel<uint><<<ab, 256, 0, stream>>>(P1f8, Q1u, offsets, (const uint*)csr, h1u, N);
    // layer 2
    gemm2_mfma<<<gb, 256, 0, stream>>>(h1u, Wp2, b2, P2f8, Q2u, N);
    if (small_idx)
        loss_kernel<u16><<<nb_loss, 1024, 0, stream>>>(P2f8, Q2u, offsets, (const u16*)csr, y, tmask, gflags, bpart, N);
    else
        loss_kernel<uint><<<nb_loss, 1024, 0, stream>>>(P2f8, Q2u, offsets, (const uint*)csr, y, tmask, gflags, bpart, N);

    finalize_kernel<<<1, 1024, 0, stream>>>(bpart, nb_loss, (float*)d_out);
}